// Round 4
// baseline (481.526 us; speedup 1.0000x reference)
//
#include <hip/hip_runtime.h>
#include <stdint.h>

// ---------------------------------------------------------------------------
// GraphAttentionLayer fused pipeline, MI355X (gfx950)
// B=64 S=512 C=512 H=4 D=128.  Split-bf16 (hi+lo) 3-term MFMA everywhere.
// Round 4: fix proj epilogue writeout (was writing only half of each tile's
// columns).  Otherwise identical to round 3: pi-permuted PV (P in registers,
// no P-LDS), V reg-staged in-attn (no transpose kernel), attn LDS 32KB.
// ---------------------------------------------------------------------------

typedef float  f32x4   __attribute__((ext_vector_type(4)));
typedef short  bf16x8  __attribute__((ext_vector_type(8)));
typedef unsigned short ushort8 __attribute__((ext_vector_type(8)));

#define GLD16(src, dst)                                                        \
  __builtin_amdgcn_global_load_lds(                                            \
      (const __attribute__((address_space(1))) void*)(src),                    \
      (__attribute__((address_space(3))) void*)(dst), 16, 0, 0)

__device__ __forceinline__ unsigned short f32_to_bf16(float x) {
  union { float f; unsigned int u; } v; v.f = x;
  unsigned int r = v.u + 0x7FFFu + ((v.u >> 16) & 1u);
  return (unsigned short)(r >> 16);
}
__device__ __forceinline__ float bf16_to_f32(unsigned short h) {
  union { float f; unsigned int u; } v; v.u = ((unsigned int)h) << 16;
  return v.f;
}
__device__ __forceinline__ f32x4 mfma16(bf16x8 a, bf16x8 b, f32x4 c) {
  return __builtin_amdgcn_mfma_f32_16x16x32_bf16(a, b, c, 0, 0, 0);
}
__device__ __forceinline__ float bperm_f(int srcLane, float v) {
  return __int_as_float(__builtin_amdgcn_ds_bpermute(srcLane << 2, __float_as_int(v)));
}

// ---------------------------------------------------------------------------
// Kernel 1: split h (fp32) -> h_hi, h_lo (bf16).  8 elems/thread.
// ---------------------------------------------------------------------------
__global__ __launch_bounds__(256) void cast_split_h(
    const float* __restrict__ src, unsigned short* __restrict__ dhi,
    unsigned short* __restrict__ dlo) {
  size_t i = ((size_t)blockIdx.x * 256 + threadIdx.x) * 8;
  f32x4 a = *(const f32x4*)(src + i);
  f32x4 b = *(const f32x4*)(src + i + 4);
  ushort8 hi, lo;
#pragma unroll
  for (int e = 0; e < 4; ++e) {
    unsigned short h0 = f32_to_bf16(a[e]);
    hi[e] = h0; lo[e] = f32_to_bf16(a[e] - bf16_to_f32(h0));
    unsigned short h1 = f32_to_bf16(b[e]);
    hi[4 + e] = h1; lo[4 + e] = f32_to_bf16(b[e] - bf16_to_f32(h1));
  }
  *(ushort8*)(dhi + i) = hi;
  *(ushort8*)(dlo + i) = lo;
}

// ---------------------------------------------------------------------------
// Kernel 2: W [H,C,D] fp32 -> Wt_hi/lo [H,D,C] bf16 (transposed per head).
// ---------------------------------------------------------------------------
__global__ __launch_bounds__(256) void cast_split_Wt(
    const float* __restrict__ W, unsigned short* __restrict__ whi,
    unsigned short* __restrict__ wlo) {
  int o = blockIdx.x * 256 + threadIdx.x;      // [0, 4*128*512)
  int hd = o >> 16;                             // head
  int rem = o & 65535;
  int d = rem >> 9;                             // [0,128)
  int c = rem & 511;                            // [0,512)
  float v = W[((size_t)(hd * 512 + c)) * 128 + d];
  unsigned short h0 = f32_to_bf16(v);
  whi[o] = h0;
  wlo[o] = f32_to_bf16(v - bf16_to_f32(h0));
}

// ---------------------------------------------------------------------------
// Kernel 3: projection GEMM  hp = h @ Wall + bias   ([32768x512]@[512x512])
// split-bf16 3-term.  128x128 tile, BK=32, 4 waves (2x2), 16x16x32 MFMA.
// Epilogue: stage through LDS (reuse Ah/Al), write hp [b*512+s][c] coalesced.
// ---------------------------------------------------------------------------
__global__ __launch_bounds__(256, 2) void proj_gemm(
    const unsigned short* __restrict__ ahi, const unsigned short* __restrict__ alo,
    const unsigned short* __restrict__ whi, const unsigned short* __restrict__ wlo,
    const float* __restrict__ bias, unsigned short* __restrict__ hp_hi,
    unsigned short* __restrict__ hp_lo) {
  int bid = blockIdx.x;
  int swz = (bid & 7) * 128 + (bid >> 3);       // XCD-contiguous work chunks
  int nt = swz & 3, mt = swz >> 2;
  int m0 = mt * 128, n0 = nt * 128;             // n-tile == head nt

  __shared__ alignas(16) unsigned short Ah[128 * 32], Al[128 * 32];
  __shared__ alignas(16) unsigned short Bh[128 * 32], Bl[128 * 32];

  int tid = threadIdx.x, wv = tid >> 6, lane = tid & 63;
  int l15 = lane & 15, l4 = lane >> 4;
  int wr = wv >> 1, wc = wv & 1;

  f32x4 acc[4][4];
#pragma unroll
  for (int a = 0; a < 4; ++a)
#pragma unroll
    for (int b = 0; b < 4; ++b) acc[a][b] = (f32x4){0.f, 0.f, 0.f, 0.f};

  for (int ks = 0; ks < 16; ++ks) {
    int k0 = ks * 32;
    for (int i = wv; i < 32; i += 4) {
      int grp = i >> 3, j = i & 7;
      int row = j * 16 + (lane >> 2);
      int off = (lane & 3) * 16;
      int sw = ((row >> 1) & 3) << 4;
      const unsigned short* sb;
      unsigned short* db;
      size_t srcoff;
      if (grp == 0)      { sb = ahi; db = Ah; srcoff = ((size_t)(m0 + row) * 512 + k0) * 2; }
      else if (grp == 1) { sb = alo; db = Al; srcoff = ((size_t)(m0 + row) * 512 + k0) * 2; }
      else if (grp == 2) { sb = whi; db = Bh; srcoff = ((size_t)(nt * 128 + row) * 512 + k0) * 2; }
      else               { sb = wlo; db = Bl; srcoff = ((size_t)(nt * 128 + row) * 512 + k0) * 2; }
      GLD16((const char*)sb + srcoff + (off ^ sw), db + j * 512);
    }
    __syncthreads();

    bf16x8 fah[4], fal[4], fbh[4], fbl[4];
#pragma unroll
    for (int f = 0; f < 4; ++f) {
      int mr = wr * 64 + f * 16 + l15;
      int aadr = mr * 64 + ((16 * l4) ^ (((mr >> 1) & 3) << 4));
      fah[f] = *(const bf16x8*)((const char*)Ah + aadr);
      fal[f] = *(const bf16x8*)((const char*)Al + aadr);
      int nr = wc * 64 + f * 16 + l15;
      int badr = nr * 64 + ((16 * l4) ^ (((nr >> 1) & 3) << 4));
      fbh[f] = *(const bf16x8*)((const char*)Bh + badr);
      fbl[f] = *(const bf16x8*)((const char*)Bl + badr);
    }
#pragma unroll
    for (int a = 0; a < 4; ++a)
#pragma unroll
      for (int b = 0; b < 4; ++b) {
        acc[a][b] = mfma16(fah[a], fbh[b], acc[a][b]);
        acc[a][b] = mfma16(fah[a], fbl[b], acc[a][b]);
        acc[a][b] = mfma16(fal[a], fbh[b], acc[a][b]);
      }
    __syncthreads();
  }

  // epilogue: +bias, RNE split, LDS-staged coalesced writes of hp rows.
  // Stage tile per a: 32 rows (wr*16 + 4*l4+r) x 128 cols, then each thread
  // moves 16 elements (two bf16x8) -> full 4096-element coverage.
#pragma unroll
  for (int a = 0; a < 4; ++a) {
    __syncthreads();
#pragma unroll
    for (int b = 0; b < 4; ++b) {
      int cloc = wc * 64 + b * 16 + l15;
      float bv = bias[n0 + cloc];
#pragma unroll
      for (int r = 0; r < 4; ++r) {
        int rloc = wr * 16 + 4 * l4 + r;
        float v = acc[a][b][r] + bv;
        unsigned short hh = f32_to_bf16(v);
        Ah[rloc * 128 + cloc] = hh;
        Al[rloc * 128 + cloc] = f32_to_bf16(v - bf16_to_f32(hh));
      }
    }
    __syncthreads();
    int rr = tid >> 3, c16 = (tid & 7) * 16;
    int mg = m0 + (rr >> 4) * 64 + a * 16 + (rr & 15);
    bf16x8 vh0 = *(const bf16x8*)(Ah + rr * 128 + c16);
    bf16x8 vh1 = *(const bf16x8*)(Ah + rr * 128 + c16 + 8);
    bf16x8 vl0 = *(const bf16x8*)(Al + rr * 128 + c16);
    bf16x8 vl1 = *(const bf16x8*)(Al + rr * 128 + c16 + 8);
    *(bf16x8*)(hp_hi + (size_t)mg * 512 + n0 + c16) = vh0;
    *(bf16x8*)(hp_hi + (size_t)mg * 512 + n0 + c16 + 8) = vh1;
    *(bf16x8*)(hp_lo + (size_t)mg * 512 + n0 + c16) = vl0;
    *(bf16x8*)(hp_lo + (size_t)mg * 512 + n0 + c16 + 8) = vl1;
  }
}

// ---------------------------------------------------------------------------
// Kernel 5: flash attention.  Block = (b, head, q-tile of 64), 4 waves x 16 q.
// Swapped QK^T (A=K, B=Q) -> lane holds q=l15, kv={4*l4+r, 16+4*l4+r}.
// pi-permuted PV: that register layout IS the PV A-frag; V B-frags are two
// ds_read_b64 at k-slots {4*l4..+3, 16+4*l4..+3}.  No P round-trip.
// Waves 0-1 stage K (GLD16); waves 2-3 reg-stage V into Vt [d][kv] (packed
// b64 column writes).  Vt swizzle: ((((d>>1)&3)^((d>>4)&3))<<4).
// ---------------------------------------------------------------------------
__global__ __launch_bounds__(256, 4) void attn_kernel(
    const unsigned short* __restrict__ hp_hi, const unsigned short* __restrict__ hp_lo,
    const float* __restrict__ adj, float* __restrict__ out) {
  int bid = blockIdx.x;
  int swz = (bid & 7) * 256 + (bid >> 3);       // 8 q-tiles of one (b,h) per XCD
  int qt = swz & 7;
  int hd = (swz >> 3) & 3;
  int bb = swz >> 5;
  int q0 = qt * 64;

  __shared__ alignas(16) unsigned short K_hi[32 * 128], K_lo[32 * 128];   // [kv][d]
  __shared__ alignas(16) unsigned short Vt_hi[128 * 32], Vt_lo[128 * 32]; // [d][kv]

  int tid = threadIdx.x, w = tid >> 6, lane = tid & 63;
  int l15 = lane & 15, l4 = lane >> 4;
  int qg = q0 + w * 16 + l15;                   // this lane's q row

  // Q fragments (B-operand: n=q at l&15, k=d contiguous), hi+lo, in registers
  bf16x8 qh[4], ql[4];
  {
    size_t base = ((size_t)bb * 512 + qg) * 512 + hd * 128 + 8 * l4;
#pragma unroll
    for (int ds = 0; ds < 4; ++ds) {
      qh[ds] = *(const bf16x8*)(hp_hi + base + ds * 32);
      ql[ds] = *(const bf16x8*)(hp_lo + base + ds * 32);
    }
  }

  f32x4 o[8];
#pragma unroll
  for (int vf = 0; vf < 8; ++vf) o[vf] = (f32x4){0.f, 0.f, 0.f, 0.f};
  float m_run = -3.0e38f, l_run = 0.f;

  // staging roles
  const unsigned short* ksb = (w == 0) ? hp_hi : hp_lo;       // waves 0-1
  unsigned short* kdb = (w == 0) ? K_hi : K_lo;
  const unsigned short* vsb = (w == 2) ? hp_hi : hp_lo;       // waves 2-3
  unsigned short* vdb = (w == 2) ? Vt_hi : Vt_lo;
  int kvg = lane >> 3, dg = lane & 7;           // V-staging coords

  for (int t = 0; t < 16; ++t) {
    int kv0 = t * 32;
    if (w < 2) {                                 // ---- K staging via GLD16
      int kvl = lane >> 4, off = (lane & 15) * 16;
#pragma unroll
      for (int j = 0; j < 8; ++j) {
        int kvr = j * 4 + kvl;
        const char* src = (const char*)ksb +
            (((size_t)(bb * 512 + kv0 + kvr)) * 512 + hd * 128) * 2 +
            (off ^ ((kvr & 7) << 4));
        GLD16(src, kdb + j * 512);
      }
    } else {                                     // ---- V reg-staging
#pragma unroll
      for (int hf = 0; hf < 2; ++hf) {
        bf16x8 L[4];
#pragma unroll
        for (int rr = 0; rr < 4; ++rr) {
          size_t row = (size_t)bb * 512 + kv0 + kvg * 4 + rr;
          L[rr] = *(const bf16x8*)(vsb + row * 512 + hd * 128 + dg * 16 + hf * 8);
        }
#pragma unroll
        for (int e = 0; e < 8; ++e) {
          int d = dg * 16 + hf * 8 + e;
          int vsw = ((((d >> 1) & 3) ^ ((d >> 4) & 3)) << 4);
          uint2 pk;
          pk.x = ((unsigned)(unsigned short)L[0][e]) |
                 (((unsigned)(unsigned short)L[1][e]) << 16);
          pk.y = ((unsigned)(unsigned short)L[2][e]) |
                 (((unsigned)(unsigned short)L[3][e]) << 16);
          *(uint2*)((char*)vdb + d * 64 + ((kvg * 8) ^ vsw)) = pk;
        }
      }
    }
    // adj loads issued before the barrier (latency hidden under stage wait)
    f32x4 av0 = *(const f32x4*)(adj + (size_t)qg * 512 + kv0 + 4 * l4);
    f32x4 av1 = *(const f32x4*)(adj + (size_t)qg * 512 + kv0 + 16 + 4 * l4);
    __syncthreads();

    // ---- scores = K @ Q^T (swapped): lane q=l15, kv = {4*l4+r, 16+4*l4+r}
    f32x4 sc0 = {0.f, 0.f, 0.f, 0.f}, sc1 = {0.f, 0.f, 0.f, 0.f};
#pragma unroll
    for (int ds = 0; ds < 4; ++ds) {
      int kb = (ds * 32 + 8 * l4) * 2;
      int r0 = l15, r1 = 16 + l15;
      int a0 = r0 * 256 + (kb ^ ((r0 & 7) << 4));
      int a1 = r1 * 256 + (kb ^ ((r1 & 7) << 4));
      bf16x8 kh0 = *(const bf16x8*)((const char*)K_hi + a0);
      bf16x8 kl0 = *(const bf16x8*)((const char*)K_lo + a0);
      bf16x8 kh1 = *(const bf16x8*)((const char*)K_hi + a1);
      bf16x8 kl1 = *(const bf16x8*)((const char*)K_lo + a1);
      sc0 = mfma16(kh0, qh[ds], sc0); sc1 = mfma16(kh1, qh[ds], sc1);
      sc0 = mfma16(kh0, ql[ds], sc0); sc1 = mfma16(kh1, ql[ds], sc1);
      sc0 = mfma16(kl0, qh[ds], sc0); sc1 = mfma16(kl1, qh[ds], sc1);
    }

    // ---- adj multiply + online softmax (row q = l15; kv in-lane)
    float p0[4], p1[4];
    float tm = -3.0e38f;
#pragma unroll
    for (int r = 0; r < 4; ++r) {
      p0[r] = sc0[r] * av0[r];
      p1[r] = sc1[r] * av1[r];
      tm = fmaxf(tm, fmaxf(p0[r], p1[r]));
    }
    tm = fmaxf(tm, __shfl_xor(tm, 16));
    tm = fmaxf(tm, __shfl_xor(tm, 32));
    if (__any(tm > m_run + 8.0f)) {             // T13 defer-rescale
      float mn = fmaxf(m_run, tm);
      float scl = __expf(m_run - mn);
      m_run = mn;
      l_run *= scl;
      f32x4 s4;
#pragma unroll
      for (int r = 0; r < 4; ++r) s4[r] = bperm_f(4 * l4 + r, scl);
#pragma unroll
      for (int vf = 0; vf < 8; ++vf)
#pragma unroll
        for (int r = 0; r < 4; ++r) o[vf][r] *= s4[r];
    }
    float ps = 0.f;
#pragma unroll
    for (int r = 0; r < 4; ++r) {
      p0[r] = __expf(p0[r] - m_run); ps += p0[r];
      p1[r] = __expf(p1[r] - m_run); ps += p1[r];
    }
    ps += __shfl_xor(ps, 16);
    ps += __shfl_xor(ps, 32);
    l_run += ps;

    // ---- pack P in-lane: A-frag slots e = {p0[0..3], p1[0..3]} (pi order)
    union PU { bf16x8 v; unsigned u[4]; } pah, pal;
#pragma unroll
    for (int i = 0; i < 4; ++i) {
      float fa = (i < 2) ? p0[2 * i] : p1[2 * (i - 2)];
      float fb = (i < 2) ? p0[2 * i + 1] : p1[2 * (i - 2) + 1];
      unsigned ua = __float_as_uint(fa), ub = __float_as_uint(fb);
      pah.u[i] = (ua >> 16) | (ub & 0xFFFF0000u);
      float la = fa - __uint_as_float(ua & 0xFFFF0000u);
      float lb = fb - __uint_as_float(ub & 0xFFFF0000u);
      pal.u[i] = (__float_as_uint(la) >> 16) | (__float_as_uint(lb) & 0xFFFF0000u);
    }

    // ---- O += P @ V (3-term), V via 2x ds_read_b64 at pi k-slots
#pragma unroll
    for (int vf = 0; vf < 8; ++vf) {
      int d = vf * 16 + l15;
      int vsw = ((((d >> 1) & 3) ^ (vf & 3)) << 4);
      const char* bh = (const char*)Vt_hi + d * 64;
      const char* bl = (const char*)Vt_lo + d * 64;
      int o1 = (8 * l4) ^ vsw, o2 = (32 + 8 * l4) ^ vsw;
      union VU { bf16x8 v; uint2 u[2]; } vh, vl;
      vh.u[0] = *(const uint2*)(bh + o1); vh.u[1] = *(const uint2*)(bh + o2);
      vl.u[0] = *(const uint2*)(bl + o1); vl.u[1] = *(const uint2*)(bl + o2);
      o[vf] = mfma16(pah.v, vh.v, o[vf]);
      o[vf] = mfma16(pah.v, vl.v, o[vf]);
      o[vf] = mfma16(pal.v, vh.v, o[vf]);
    }
    __syncthreads();   // protect K/Vt from next tile's staging
  }

  // ---- epilogue: divide by row sums (bpermute redistribution), write fp32
  float rinv = 1.0f / l_run;
  f32x4 r4;
#pragma unroll
  for (int r = 0; r < 4; ++r) r4[r] = bperm_f(4 * l4 + r, rinv);
#pragma unroll
  for (int vf = 0; vf < 8; ++vf)
#pragma unroll
    for (int r = 0; r < 4; ++r) {
      size_t mg = (size_t)bb * 512 + q0 + w * 16 + 4 * l4 + r;
      out[mg * 512 + hd * 128 + vf * 16 + l15] = o[vf][r] * r4[r];
    }
}

// ---------------------------------------------------------------------------
// Kernel 6: LayerNorm (over C=512) + exact-erf GELU, in place on d_out.
// ---------------------------------------------------------------------------
__global__ __launch_bounds__(256) void ln_gelu_kernel(
    float* __restrict__ io, const float* __restrict__ gamma,
    const float* __restrict__ beta) {
  int w = threadIdx.x >> 6, lane = threadIdx.x & 63;
  size_t row = (size_t)blockIdx.x * 4 + w;
  float* p = io + row * 512;
  f32x4 x0 = *(const f32x4*)(p + lane * 8);
  f32x4 x1 = *(const f32x4*)(p + lane * 8 + 4);
  float s = x0[0] + x0[1] + x0[2] + x0[3] + x1[0] + x1[1] + x1[2] + x1[3];
#pragma unroll
  for (int off = 32; off >= 1; off >>= 1) s += __shfl_xor(s, off);
  float mu = s * (1.0f / 512.0f);
  float vs = 0.f;
#pragma unroll
  for (int e = 0; e < 4; ++e) {
    float d0 = x0[e] - mu; vs += d0 * d0;
    float d1 = x1[e] - mu; vs += d1 * d1;
  }
#pragma unroll
  for (int off = 32; off >= 1; off >>= 1) vs += __shfl_xor(vs, off);
  float rs = rsqrtf(vs * (1.0f / 512.0f) + 1e-5f);
  f32x4 g0 = *(const f32x4*)(gamma + lane * 8);
  f32x4 g1 = *(const f32x4*)(gamma + lane * 8 + 4);
  f32x4 b0 = *(const f32x4*)(beta + lane * 8);
  f32x4 b1 = *(const f32x4*)(beta + lane * 8 + 4);
  f32x4 y0, y1;
#pragma unroll
  for (int e = 0; e < 4; ++e) {
    float y = (x0[e] - mu) * rs * g0[e] + b0[e];
    y0[e] = 0.5f * y * (1.0f + erff(y * 0.70710678118654752f));
    float z = (x1[e] - mu) * rs * g1[e] + b1[e];
    y1[e] = 0.5f * z * (1.0f + erff(z * 0.70710678118654752f));
  }
  *(f32x4*)(p + lane * 8) = y0;
  *(f32x4*)(p + lane * 8 + 4) = y1;
}

// ---------------------------------------------------------------------------
// Host launcher.  Inputs: [0]=t [1]=h [2]=W [3]=b [4]=adj [5]=gamma [6]=beta
// Workspace (~135 MB):
//   h_hi   = ws + 0          (16.7M u16)
//   h_lo   = ws + 16777216
//   hp_hi  = ws + 33554432
//   hp_lo  = ws + 50331648
//   Wt_hi  = ws + 67108864   (262144 u16)
//   Wt_lo  = ws + 67371008
// ---------------------------------------------------------------------------
extern "C" void kernel_launch(void* const* d_in, const int* in_sizes, int n_in,
                              void* d_out, int out_size, void* d_ws, size_t ws_size,
                              hipStream_t stream) {
  const float* h     = (const float*)d_in[1];
  const float* W     = (const float*)d_in[2];
  const float* bias  = (const float*)d_in[3];
  const float* adj   = (const float*)d_in[4];
  const float* gamma = (const float*)d_in[5];
  const float* beta  = (const float*)d_in[6];
  float* out = (float*)d_out;

  unsigned short* ws = (unsigned short*)d_ws;
  unsigned short* h_hi   = ws;
  unsigned short* h_lo   = ws + 16777216;
  unsigned short* hp_hi  = ws + 33554432;
  unsigned short* hp_lo  = ws + 50331648;
  unsigned short* Wt_hi  = ws + 67108864;
  unsigned short* Wt_lo  = ws + 67371008;

  cast_split_h<<<8192, 256, 0, stream>>>(h, h_hi, h_lo);
  cast_split_Wt<<<1024, 256, 0, stream>>>(W, Wt_hi, Wt_lo);
  proj_gemm<<<1024, 256, 0, stream>>>(h_hi, h_lo, Wt_hi, Wt_lo, bias, hp_hi, hp_lo);
  attn_kernel<<<2048, 256, 0, stream>>>(hp_hi, hp_lo, adj, out);
  ln_gelu_kernel<<<8192, 256, 0, stream>>>(out, gamma, beta);
}

// Round 5
// 447.615 us; speedup vs baseline: 1.0758x; 1.0758x over previous
//
#include <hip/hip_runtime.h>
#include <stdint.h>

// ---------------------------------------------------------------------------
// GraphAttentionLayer fused pipeline, MI355X (gfx950)
// B=64 S=512 C=512 H=4 D=128.  Split-bf16 (hi+lo) 3-term MFMA everywhere.
// Round 5: attn stages K once (GLD16, coalesced) and builds Vt by LDS
// transpose of K_lds (V global reads deleted -> half the hp traffic).
// Coalesced LDS-staged O writeout (kills write amplification).  pi-PV kept.
// ---------------------------------------------------------------------------

typedef float  f32x4   __attribute__((ext_vector_type(4)));
typedef short  bf16x8  __attribute__((ext_vector_type(8)));
typedef unsigned short ushort8 __attribute__((ext_vector_type(8)));

#define GLD16(src, dst)                                                        \
  __builtin_amdgcn_global_load_lds(                                            \
      (const __attribute__((address_space(1))) void*)(src),                    \
      (__attribute__((address_space(3))) void*)(dst), 16, 0, 0)

__device__ __forceinline__ unsigned short f32_to_bf16(float x) {
  union { float f; unsigned int u; } v; v.f = x;
  unsigned int r = v.u + 0x7FFFu + ((v.u >> 16) & 1u);
  return (unsigned short)(r >> 16);
}
__device__ __forceinline__ float bf16_to_f32(unsigned short h) {
  union { float f; unsigned int u; } v; v.u = ((unsigned int)h) << 16;
  return v.f;
}
__device__ __forceinline__ f32x4 mfma16(bf16x8 a, bf16x8 b, f32x4 c) {
  return __builtin_amdgcn_mfma_f32_16x16x32_bf16(a, b, c, 0, 0, 0);
}
__device__ __forceinline__ float bperm_f(int srcLane, float v) {
  return __int_as_float(__builtin_amdgcn_ds_bpermute(srcLane << 2, __float_as_int(v)));
}

// ---------------------------------------------------------------------------
// Kernel 1: split h (fp32) -> h_hi, h_lo (bf16).  8 elems/thread.
// ---------------------------------------------------------------------------
__global__ __launch_bounds__(256) void cast_split_h(
    const float* __restrict__ src, unsigned short* __restrict__ dhi,
    unsigned short* __restrict__ dlo) {
  size_t i = ((size_t)blockIdx.x * 256 + threadIdx.x) * 8;
  f32x4 a = *(const f32x4*)(src + i);
  f32x4 b = *(const f32x4*)(src + i + 4);
  ushort8 hi, lo;
#pragma unroll
  for (int e = 0; e < 4; ++e) {
    unsigned short h0 = f32_to_bf16(a[e]);
    hi[e] = h0; lo[e] = f32_to_bf16(a[e] - bf16_to_f32(h0));
    unsigned short h1 = f32_to_bf16(b[e]);
    hi[4 + e] = h1; lo[4 + e] = f32_to_bf16(b[e] - bf16_to_f32(h1));
  }
  *(ushort8*)(dhi + i) = hi;
  *(ushort8*)(dlo + i) = lo;
}

// ---------------------------------------------------------------------------
// Kernel 2: W [H,C,D] fp32 -> Wt_hi/lo [H,D,C] bf16 (transposed per head).
// ---------------------------------------------------------------------------
__global__ __launch_bounds__(256) void cast_split_Wt(
    const float* __restrict__ W, unsigned short* __restrict__ whi,
    unsigned short* __restrict__ wlo) {
  int o = blockIdx.x * 256 + threadIdx.x;      // [0, 4*128*512)
  int hd = o >> 16;                             // head
  int rem = o & 65535;
  int d = rem >> 9;                             // [0,128)
  int c = rem & 511;                            // [0,512)
  float v = W[((size_t)(hd * 512 + c)) * 128 + d];
  unsigned short h0 = f32_to_bf16(v);
  whi[o] = h0;
  wlo[o] = f32_to_bf16(v - bf16_to_f32(h0));
}

// ---------------------------------------------------------------------------
// Kernel 3: projection GEMM  hp = h @ Wall + bias   ([32768x512]@[512x512])
// split-bf16 3-term.  128x128 tile, BK=32, 4 waves (2x2), 16x16x32 MFMA.
// Epilogue: stage through LDS (reuse Ah/Al), write hp [b*512+s][c] coalesced.
// ---------------------------------------------------------------------------
__global__ __launch_bounds__(256, 2) void proj_gemm(
    const unsigned short* __restrict__ ahi, const unsigned short* __restrict__ alo,
    const unsigned short* __restrict__ whi, const unsigned short* __restrict__ wlo,
    const float* __restrict__ bias, unsigned short* __restrict__ hp_hi,
    unsigned short* __restrict__ hp_lo) {
  int bid = blockIdx.x;
  int swz = (bid & 7) * 128 + (bid >> 3);       // XCD-contiguous work chunks
  int nt = swz & 3, mt = swz >> 2;
  int m0 = mt * 128, n0 = nt * 128;             // n-tile == head nt

  __shared__ alignas(16) unsigned short Ah[128 * 32], Al[128 * 32];
  __shared__ alignas(16) unsigned short Bh[128 * 32], Bl[128 * 32];

  int tid = threadIdx.x, wv = tid >> 6, lane = tid & 63;
  int l15 = lane & 15, l4 = lane >> 4;
  int wr = wv >> 1, wc = wv & 1;

  f32x4 acc[4][4];
#pragma unroll
  for (int a = 0; a < 4; ++a)
#pragma unroll
    for (int b = 0; b < 4; ++b) acc[a][b] = (f32x4){0.f, 0.f, 0.f, 0.f};

  for (int ks = 0; ks < 16; ++ks) {
    int k0 = ks * 32;
    for (int i = wv; i < 32; i += 4) {
      int grp = i >> 3, j = i & 7;
      int row = j * 16 + (lane >> 2);
      int off = (lane & 3) * 16;
      int sw = ((row >> 1) & 3) << 4;
      const unsigned short* sb;
      unsigned short* db;
      size_t srcoff;
      if (grp == 0)      { sb = ahi; db = Ah; srcoff = ((size_t)(m0 + row) * 512 + k0) * 2; }
      else if (grp == 1) { sb = alo; db = Al; srcoff = ((size_t)(m0 + row) * 512 + k0) * 2; }
      else if (grp == 2) { sb = whi; db = Bh; srcoff = ((size_t)(nt * 128 + row) * 512 + k0) * 2; }
      else               { sb = wlo; db = Bl; srcoff = ((size_t)(nt * 128 + row) * 512 + k0) * 2; }
      GLD16((const char*)sb + srcoff + (off ^ sw), db + j * 512);
    }
    __syncthreads();

    bf16x8 fah[4], fal[4], fbh[4], fbl[4];
#pragma unroll
    for (int f = 0; f < 4; ++f) {
      int mr = wr * 64 + f * 16 + l15;
      int aadr = mr * 64 + ((16 * l4) ^ (((mr >> 1) & 3) << 4));
      fah[f] = *(const bf16x8*)((const char*)Ah + aadr);
      fal[f] = *(const bf16x8*)((const char*)Al + aadr);
      int nr = wc * 64 + f * 16 + l15;
      int badr = nr * 64 + ((16 * l4) ^ (((nr >> 1) & 3) << 4));
      fbh[f] = *(const bf16x8*)((const char*)Bh + badr);
      fbl[f] = *(const bf16x8*)((const char*)Bl + badr);
    }
#pragma unroll
    for (int a = 0; a < 4; ++a)
#pragma unroll
      for (int b = 0; b < 4; ++b) {
        acc[a][b] = mfma16(fah[a], fbh[b], acc[a][b]);
        acc[a][b] = mfma16(fah[a], fbl[b], acc[a][b]);
        acc[a][b] = mfma16(fal[a], fbh[b], acc[a][b]);
      }
    __syncthreads();
  }

  // epilogue: +bias, RNE split, LDS-staged coalesced writes of hp rows.
#pragma unroll
  for (int a = 0; a < 4; ++a) {
    __syncthreads();
#pragma unroll
    for (int b = 0; b < 4; ++b) {
      int cloc = wc * 64 + b * 16 + l15;
      float bv = bias[n0 + cloc];
#pragma unroll
      for (int r = 0; r < 4; ++r) {
        int rloc = wr * 16 + 4 * l4 + r;
        float v = acc[a][b][r] + bv;
        unsigned short hh = f32_to_bf16(v);
        Ah[rloc * 128 + cloc] = hh;
        Al[rloc * 128 + cloc] = f32_to_bf16(v - bf16_to_f32(hh));
      }
    }
    __syncthreads();
    int rr = tid >> 3, c16 = (tid & 7) * 16;
    int mg = m0 + (rr >> 4) * 64 + a * 16 + (rr & 15);
    bf16x8 vh0 = *(const bf16x8*)(Ah + rr * 128 + c16);
    bf16x8 vh1 = *(const bf16x8*)(Ah + rr * 128 + c16 + 8);
    bf16x8 vl0 = *(const bf16x8*)(Al + rr * 128 + c16);
    bf16x8 vl1 = *(const bf16x8*)(Al + rr * 128 + c16 + 8);
    *(bf16x8*)(hp_hi + (size_t)mg * 512 + n0 + c16) = vh0;
    *(bf16x8*)(hp_hi + (size_t)mg * 512 + n0 + c16 + 8) = vh1;
    *(bf16x8*)(hp_lo + (size_t)mg * 512 + n0 + c16) = vl0;
    *(bf16x8*)(hp_lo + (size_t)mg * 512 + n0 + c16 + 8) = vl1;
  }
}

// ---------------------------------------------------------------------------
// Kernel 5: flash attention.  Block = (b, head, q-tile of 64), 4 waves x 16 q.
// K staged ONCE per kv-tile via GLD16 (4 insts/wave); Vt built from K_lds by
// an in-LDS transpose (V never re-read from HBM).  Swapped QK^T + pi-PV with
// P in registers.  Epilogue stages O through LDS for coalesced f32 writes.
// LDS = 32 KB.  2 barriers per kv-tile.
// ---------------------------------------------------------------------------
__global__ __launch_bounds__(256, 4) void attn_kernel(
    const unsigned short* __restrict__ hp_hi, const unsigned short* __restrict__ hp_lo,
    const float* __restrict__ adj, float* __restrict__ out) {
  int bid = blockIdx.x;
  int swz = (bid & 7) * 256 + (bid >> 3);       // 8 q-tiles of one (b,h) per XCD
  int qt = swz & 7;
  int hd = (swz >> 3) & 3;
  int bb = swz >> 5;
  int q0 = qt * 64;

  __shared__ alignas(16) unsigned short SM[16384];     // 32 KB
  unsigned short* K_hi  = SM;            // [32][128] swizzled
  unsigned short* K_lo  = SM + 4096;
  unsigned short* Vt_hi = SM + 8192;     // [128][32] swizzled
  unsigned short* Vt_lo = SM + 12288;

  int tid = threadIdx.x, w = tid >> 6, lane = tid & 63;
  int l15 = lane & 15, l4 = lane >> 4;
  int qg = q0 + w * 16 + l15;                   // this lane's softmax q row

  // Q fragments (B-operand: n=q at l&15, k=d contiguous), hi+lo, in registers
  bf16x8 qh[4], ql[4];
  {
    size_t base = ((size_t)bb * 512 + qg) * 512 + hd * 128 + 8 * l4;
#pragma unroll
    for (int ds = 0; ds < 4; ++ds) {
      qh[ds] = *(const bf16x8*)(hp_hi + base + ds * 32);
      ql[ds] = *(const bf16x8*)(hp_lo + base + ds * 32);
    }
  }

  f32x4 o[8];
#pragma unroll
  for (int vf = 0; vf < 8; ++vf) o[vf] = (f32x4){0.f, 0.f, 0.f, 0.f};
  float m_run = -3.0e38f, l_run = 0.f;

  // K staging role: w0: K_hi j0-3, w1: K_hi j4-7, w2: K_lo j0-3, w3: K_lo j4-7
  const unsigned short* ksb = (w & 2) ? hp_lo : hp_hi;
  unsigned short* kdb = (w & 2) ? K_lo : K_hi;
  int jbase = (w & 1) * 4;
  // Vt transpose role: w0: Vt_hi hf0, w1: Vt_hi hf1, w2: Vt_lo hf0, w3: Vt_lo hf1
  const unsigned short* tK = (w & 2) ? K_lo : K_hi;
  unsigned short* tV = (w & 2) ? Vt_lo : Vt_hi;
  int hf = w & 1;
  int kvg = lane >> 3, dg = lane & 7;           // transpose coords

  for (int t = 0; t < 16; ++t) {
    int kv0 = t * 32;
    // ---- stage K tile (hi+lo) via GLD16, 4 insts per wave
    {
      int kvl = lane >> 4, off = (lane & 15) * 16;
#pragma unroll
      for (int j2 = 0; j2 < 4; ++j2) {
        int j = jbase + j2;
        int kvr = j * 4 + kvl;
        const char* src = (const char*)ksb +
            (((size_t)(bb * 512 + kv0 + kvr)) * 512 + hd * 128) * 2 +
            (off ^ ((kvr & 7) << 4));
        GLD16(src, kdb + j * 512);
      }
    }
    // adj loads issued before the barrier (latency hidden under stage wait)
    f32x4 av0 = *(const f32x4*)(adj + (size_t)qg * 512 + kv0 + 4 * l4);
    f32x4 av1 = *(const f32x4*)(adj + (size_t)qg * 512 + kv0 + 16 + 4 * l4);
    __syncthreads();                            // K_lds ready

    // ---- build Vt quarter from K_lds (in-LDS transpose via registers)
    {
      bf16x8 L[4];
#pragma unroll
      for (int rr = 0; rr < 4; ++rr) {
        int kvr = kvg * 4 + rr;
        L[rr] = *(const bf16x8*)((const char*)tK + kvr * 256 +
                                 ((dg * 32 + hf * 16) ^ ((kvr & 7) << 4)));
      }
#pragma unroll
      for (int e = 0; e < 8; ++e) {
        int d = dg * 16 + hf * 8 + e;
        int vsw = ((((d >> 1) & 3) ^ ((d >> 4) & 3)) << 4);
        uint2 pk;
        pk.x = ((unsigned)(unsigned short)L[0][e]) |
               (((unsigned)(unsigned short)L[1][e]) << 16);
        pk.y = ((unsigned)(unsigned short)L[2][e]) |
               (((unsigned)(unsigned short)L[3][e]) << 16);
        *(uint2*)((char*)tV + d * 64 + ((kvg * 8) ^ vsw)) = pk;
      }
    }

    // ---- scores = K @ Q^T (swapped): lane q=l15, kv = {4*l4+r, 16+4*l4+r}
    f32x4 sc0 = {0.f, 0.f, 0.f, 0.f}, sc1 = {0.f, 0.f, 0.f, 0.f};
#pragma unroll
    for (int ds = 0; ds < 4; ++ds) {
      int kb = (ds * 32 + 8 * l4) * 2;
      int r0 = l15, r1 = 16 + l15;
      int a0 = r0 * 256 + (kb ^ ((r0 & 7) << 4));
      int a1 = r1 * 256 + (kb ^ ((r1 & 7) << 4));
      bf16x8 kh0 = *(const bf16x8*)((const char*)K_hi + a0);
      bf16x8 kl0 = *(const bf16x8*)((const char*)K_lo + a0);
      bf16x8 kh1 = *(const bf16x8*)((const char*)K_hi + a1);
      bf16x8 kl1 = *(const bf16x8*)((const char*)K_lo + a1);
      sc0 = mfma16(kh0, qh[ds], sc0); sc1 = mfma16(kh1, qh[ds], sc1);
      sc0 = mfma16(kh0, ql[ds], sc0); sc1 = mfma16(kh1, ql[ds], sc1);
      sc0 = mfma16(kl0, qh[ds], sc0); sc1 = mfma16(kl1, qh[ds], sc1);
    }

    // ---- adj multiply + online softmax (row q = l15; kv in-lane)
    float p0[4], p1[4];
    float tm = -3.0e38f;
#pragma unroll
    for (int r = 0; r < 4; ++r) {
      p0[r] = sc0[r] * av0[r];
      p1[r] = sc1[r] * av1[r];
      tm = fmaxf(tm, fmaxf(p0[r], p1[r]));
    }
    tm = fmaxf(tm, __shfl_xor(tm, 16));
    tm = fmaxf(tm, __shfl_xor(tm, 32));
    if (__any(tm > m_run + 8.0f)) {             // T13 defer-rescale
      float mn = fmaxf(m_run, tm);
      float scl = __expf(m_run - mn);
      m_run = mn;
      l_run *= scl;
      f32x4 s4;
#pragma unroll
      for (int r = 0; r < 4; ++r) s4[r] = bperm_f(4 * l4 + r, scl);
#pragma unroll
      for (int vf = 0; vf < 8; ++vf)
#pragma unroll
        for (int r = 0; r < 4; ++r) o[vf][r] *= s4[r];
    }
    float ps = 0.f;
#pragma unroll
    for (int r = 0; r < 4; ++r) {
      p0[r] = __expf(p0[r] - m_run); ps += p0[r];
      p1[r] = __expf(p1[r] - m_run); ps += p1[r];
    }
    ps += __shfl_xor(ps, 16);
    ps += __shfl_xor(ps, 32);
    l_run += ps;

    // ---- pack P in-lane: A-frag slots e = {p0[0..3], p1[0..3]} (pi order)
    union PU { bf16x8 v; unsigned u[4]; } pah, pal;
#pragma unroll
    for (int i = 0; i < 4; ++i) {
      float fa = (i < 2) ? p0[2 * i] : p1[2 * (i - 2)];
      float fb = (i < 2) ? p0[2 * i + 1] : p1[2 * (i - 2) + 1];
      unsigned ua = __float_as_uint(fa), ub = __float_as_uint(fb);
      pah.u[i] = (ua >> 16) | (ub & 0xFFFF0000u);
      float la = fa - __uint_as_float(ua & 0xFFFF0000u);
      float lb = fb - __uint_as_float(ub & 0xFFFF0000u);
      pal.u[i] = (__float_as_uint(la) >> 16) | (__float_as_uint(lb) & 0xFFFF0000u);
    }

    __syncthreads();                            // Vt ready; K reads done

    // ---- O += P @ V (3-term), V via 2x ds_read_b64 at pi k-slots
#pragma unroll
    for (int vf = 0; vf < 8; ++vf) {
      int d = vf * 16 + l15;
      int vsw = ((((d >> 1) & 3) ^ (vf & 3)) << 4);
      const char* bh = (const char*)Vt_hi + d * 64;
      const char* bl = (const char*)Vt_lo + d * 64;
      int o1 = (8 * l4) ^ vsw, o2 = (32 + 8 * l4) ^ vsw;
      union VU { bf16x8 v; uint2 u[2]; } vh, vl;
      vh.u[0] = *(const uint2*)(bh + o1); vh.u[1] = *(const uint2*)(bh + o2);
      vl.u[0] = *(const uint2*)(bl + o1); vl.u[1] = *(const uint2*)(bl + o2);
      o[vf] = mfma16(pah.v, vh.v, o[vf]);
      o[vf] = mfma16(pah.v, vl.v, o[vf]);
      o[vf] = mfma16(pal.v, vh.v, o[vf]);
    }
    // next iteration's GLD16 writes K only (PV stragglers read Vt only);
    // next iteration's barrier-1 gates Vt overwrite.  No trailing barrier.
  }

  // ---- epilogue: divide by row sums, stage O in LDS, coalesced f32 writes
  float rinv = 1.0f / l_run;
  f32x4 r4;
#pragma unroll
  for (int r = 0; r < 4; ++r) r4[r] = bperm_f(4 * l4 + r, rinv);
  __syncthreads();                              // all PV reads of SM done
  float* wbase = (float*)SM + w * 2048;         // [16][128] f32 per wave
#pragma unroll
  for (int vf = 0; vf < 8; ++vf)
#pragma unroll
    for (int r = 0; r < 4; ++r)
      wbase[(4 * l4 + r) * 128 + vf * 16 + l15] = o[vf][r] * r4[r];
  __syncthreads();                              // also fences the alias write
#pragma unroll
  for (int p = 0; p < 4; ++p) {
    int row = p * 4 + l4;
    f32x4 v0 = *(const f32x4*)(wbase + row * 128 + l15 * 8);
    f32x4 v1 = *(const f32x4*)(wbase + row * 128 + l15 * 8 + 4);
    size_t mg = (size_t)bb * 512 + q0 + w * 16 + row;
    float* op = out + mg * 512 + hd * 128 + l15 * 8;
    *(f32x4*)op = v0;
    *(f32x4*)(op + 4) = v1;
  }
}

// ---------------------------------------------------------------------------
// Kernel 6: LayerNorm (over C=512) + exact-erf GELU, in place on d_out.
// ---------------------------------------------------------------------------
__global__ __launch_bounds__(256) void ln_gelu_kernel(
    float* __restrict__ io, const float* __restrict__ gamma,
    const float* __restrict__ beta) {
  int w = threadIdx.x >> 6, lane = threadIdx.x & 63;
  size_t row = (size_t)blockIdx.x * 4 + w;
  float* p = io + row * 512;
  f32x4 x0 = *(const f32x4*)(p + lane * 8);
  f32x4 x1 = *(const f32x4*)(p + lane * 8 + 4);
  float s = x0[0] + x0[1] + x0[2] + x0[3] + x1[0] + x1[1] + x1[2] + x1[3];
#pragma unroll
  for (int off = 32; off >= 1; off >>= 1) s += __shfl_xor(s, off);
  float mu = s * (1.0f / 512.0f);
  float vs = 0.f;
#pragma unroll
  for (int e = 0; e < 4; ++e) {
    float d0 = x0[e] - mu; vs += d0 * d0;
    float d1 = x1[e] - mu; vs += d1 * d1;
  }
#pragma unroll
  for (int off = 32; off >= 1; off >>= 1) vs += __shfl_xor(vs, off);
  float rs = rsqrtf(vs * (1.0f / 512.0f) + 1e-5f);
  f32x4 g0 = *(const f32x4*)(gamma + lane * 8);
  f32x4 g1 = *(const f32x4*)(gamma + lane * 8 + 4);
  f32x4 b0 = *(const f32x4*)(beta + lane * 8);
  f32x4 b1 = *(const f32x4*)(beta + lane * 8 + 4);
  f32x4 y0, y1;
#pragma unroll
  for (int e = 0; e < 4; ++e) {
    float y = (x0[e] - mu) * rs * g0[e] + b0[e];
    y0[e] = 0.5f * y * (1.0f + erff(y * 0.70710678118654752f));
    float z = (x1[e] - mu) * rs * g1[e] + b1[e];
    y1[e] = 0.5f * z * (1.0f + erff(z * 0.70710678118654752f));
  }
  *(f32x4*)(p + lane * 8) = y0;
  *(f32x4*)(p + lane * 8 + 4) = y1;
}

// ---------------------------------------------------------------------------
// Host launcher.  Inputs: [0]=t [1]=h [2]=W [3]=b [4]=adj [5]=gamma [6]=beta
// Workspace (~135 MB):
//   h_hi   = ws + 0          (16.7M u16)
//   h_lo   = ws + 16777216
//   hp_hi  = ws + 33554432
//   hp_lo  = ws + 50331648
//   Wt_hi  = ws + 67108864   (262144 u16)
//   Wt_lo  = ws + 67371008
// ---------------------------------------------------------------------------
extern "C" void kernel_launch(void* const* d_in, const int* in_sizes, int n_in,
                              void* d_out, int out_size, void* d_ws, size_t ws_size,
                              hipStream_t stream) {
  const float* h     = (const float*)d_in[1];
  const float* W     = (const float*)d_in[2];
  const float* bias  = (const float*)d_in[3];
  const float* adj   = (const float*)d_in[4];
  const float* gamma = (const float*)d_in[5];
  const float* beta  = (const float*)d_in[6];
  float* out = (float*)d_out;

  unsigned short* ws = (unsigned short*)d_ws;
  unsigned short* h_hi   = ws;
  unsigned short* h_lo   = ws + 16777216;
  unsigned short* hp_hi  = ws + 33554432;
  unsigned short* hp_lo  = ws + 50331648;
  unsigned short* Wt_hi  = ws + 67108864;
  unsigned short* Wt_lo  = ws + 67371008;

  cast_split_h<<<8192, 256, 0, stream>>>(h, h_hi, h_lo);
  cast_split_Wt<<<1024, 256, 0, stream>>>(W, Wt_hi, Wt_lo);
  proj_gemm<<<1024, 256, 0, stream>>>(h_hi, h_lo, Wt_hi, Wt_lo, bias, hp_hi, hp_lo);
  attn_kernel<<<2048, 256, 0, stream>>>(hp_hi, hp_lo, adj, out);
  ln_gelu_kernel<<<8192, 256, 0, stream>>>(out, gamma, beta);
}

// Round 6
// 291.112 us; speedup vs baseline: 1.6541x; 1.5376x over previous
//
#include <hip/hip_runtime.h>
#include <stdint.h>

// ---------------------------------------------------------------------------
// GraphAttentionLayer fused pipeline, MI355X (gfx950)
// B=64 S=512 C=512 H=4 D=128.  Split-bf16 (hi+lo) 3-term MFMA everywhere.
// Round 6: single-variable experiment vs round 5 — cap attn at 2 blocks/CU
// (LDS padded to 56KB + __launch_bounds__(256,2)) to restore per-XCD L2
// capture of the K/adj streams (round-2 regime).  Kernel loop unchanged.
// ---------------------------------------------------------------------------

typedef float  f32x4   __attribute__((ext_vector_type(4)));
typedef short  bf16x8  __attribute__((ext_vector_type(8)));
typedef unsigned short ushort8 __attribute__((ext_vector_type(8)));

#define GLD16(src, dst)                                                        \
  __builtin_amdgcn_global_load_lds(                                            \
      (const __attribute__((address_space(1))) void*)(src),                    \
      (__attribute__((address_space(3))) void*)(dst), 16, 0, 0)

__device__ __forceinline__ unsigned short f32_to_bf16(float x) {
  union { float f; unsigned int u; } v; v.f = x;
  unsigned int r = v.u + 0x7FFFu + ((v.u >> 16) & 1u);
  return (unsigned short)(r >> 16);
}
__device__ __forceinline__ float bf16_to_f32(unsigned short h) {
  union { float f; unsigned int u; } v; v.u = ((unsigned int)h) << 16;
  return v.f;
}
__device__ __forceinline__ f32x4 mfma16(bf16x8 a, bf16x8 b, f32x4 c) {
  return __builtin_amdgcn_mfma_f32_16x16x32_bf16(a, b, c, 0, 0, 0);
}
__device__ __forceinline__ float bperm_f(int srcLane, float v) {
  return __int_as_float(__builtin_amdgcn_ds_bpermute(srcLane << 2, __float_as_int(v)));
}

// ---------------------------------------------------------------------------
// Kernel 1: split h (fp32) -> h_hi, h_lo (bf16).  8 elems/thread.
// ---------------------------------------------------------------------------
__global__ __launch_bounds__(256) void cast_split_h(
    const float* __restrict__ src, unsigned short* __restrict__ dhi,
    unsigned short* __restrict__ dlo) {
  size_t i = ((size_t)blockIdx.x * 256 + threadIdx.x) * 8;
  f32x4 a = *(const f32x4*)(src + i);
  f32x4 b = *(const f32x4*)(src + i + 4);
  ushort8 hi, lo;
#pragma unroll
  for (int e = 0; e < 4; ++e) {
    unsigned short h0 = f32_to_bf16(a[e]);
    hi[e] = h0; lo[e] = f32_to_bf16(a[e] - bf16_to_f32(h0));
    unsigned short h1 = f32_to_bf16(b[e]);
    hi[4 + e] = h1; lo[4 + e] = f32_to_bf16(b[e] - bf16_to_f32(h1));
  }
  *(ushort8*)(dhi + i) = hi;
  *(ushort8*)(dlo + i) = lo;
}

// ---------------------------------------------------------------------------
// Kernel 2: W [H,C,D] fp32 -> Wt_hi/lo [H,D,C] bf16 (transposed per head).
// ---------------------------------------------------------------------------
__global__ __launch_bounds__(256) void cast_split_Wt(
    const float* __restrict__ W, unsigned short* __restrict__ whi,
    unsigned short* __restrict__ wlo) {
  int o = blockIdx.x * 256 + threadIdx.x;      // [0, 4*128*512)
  int hd = o >> 16;                             // head
  int rem = o & 65535;
  int d = rem >> 9;                             // [0,128)
  int c = rem & 511;                            // [0,512)
  float v = W[((size_t)(hd * 512 + c)) * 128 + d];
  unsigned short h0 = f32_to_bf16(v);
  whi[o] = h0;
  wlo[o] = f32_to_bf16(v - bf16_to_f32(h0));
}

// ---------------------------------------------------------------------------
// Kernel 3: projection GEMM  hp = h @ Wall + bias   ([32768x512]@[512x512])
// split-bf16 3-term.  128x128 tile, BK=32, 4 waves (2x2), 16x16x32 MFMA.
// Epilogue: stage through LDS (reuse Ah/Al), write hp [b*512+s][c] coalesced.
// ---------------------------------------------------------------------------
__global__ __launch_bounds__(256, 2) void proj_gemm(
    const unsigned short* __restrict__ ahi, const unsigned short* __restrict__ alo,
    const unsigned short* __restrict__ whi, const unsigned short* __restrict__ wlo,
    const float* __restrict__ bias, unsigned short* __restrict__ hp_hi,
    unsigned short* __restrict__ hp_lo) {
  int bid = blockIdx.x;
  int swz = (bid & 7) * 128 + (bid >> 3);       // XCD-contiguous work chunks
  int nt = swz & 3, mt = swz >> 2;
  int m0 = mt * 128, n0 = nt * 128;             // n-tile == head nt

  __shared__ alignas(16) unsigned short Ah[128 * 32], Al[128 * 32];
  __shared__ alignas(16) unsigned short Bh[128 * 32], Bl[128 * 32];

  int tid = threadIdx.x, wv = tid >> 6, lane = tid & 63;
  int l15 = lane & 15, l4 = lane >> 4;
  int wr = wv >> 1, wc = wv & 1;

  f32x4 acc[4][4];
#pragma unroll
  for (int a = 0; a < 4; ++a)
#pragma unroll
    for (int b = 0; b < 4; ++b) acc[a][b] = (f32x4){0.f, 0.f, 0.f, 0.f};

  for (int ks = 0; ks < 16; ++ks) {
    int k0 = ks * 32;
    for (int i = wv; i < 32; i += 4) {
      int grp = i >> 3, j = i & 7;
      int row = j * 16 + (lane >> 2);
      int off = (lane & 3) * 16;
      int sw = ((row >> 1) & 3) << 4;
      const unsigned short* sb;
      unsigned short* db;
      size_t srcoff;
      if (grp == 0)      { sb = ahi; db = Ah; srcoff = ((size_t)(m0 + row) * 512 + k0) * 2; }
      else if (grp == 1) { sb = alo; db = Al; srcoff = ((size_t)(m0 + row) * 512 + k0) * 2; }
      else if (grp == 2) { sb = whi; db = Bh; srcoff = ((size_t)(nt * 128 + row) * 512 + k0) * 2; }
      else               { sb = wlo; db = Bl; srcoff = ((size_t)(nt * 128 + row) * 512 + k0) * 2; }
      GLD16((const char*)sb + srcoff + (off ^ sw), db + j * 512);
    }
    __syncthreads();

    bf16x8 fah[4], fal[4], fbh[4], fbl[4];
#pragma unroll
    for (int f = 0; f < 4; ++f) {
      int mr = wr * 64 + f * 16 + l15;
      int aadr = mr * 64 + ((16 * l4) ^ (((mr >> 1) & 3) << 4));
      fah[f] = *(const bf16x8*)((const char*)Ah + aadr);
      fal[f] = *(const bf16x8*)((const char*)Al + aadr);
      int nr = wc * 64 + f * 16 + l15;
      int badr = nr * 64 + ((16 * l4) ^ (((nr >> 1) & 3) << 4));
      fbh[f] = *(const bf16x8*)((const char*)Bh + badr);
      fbl[f] = *(const bf16x8*)((const char*)Bl + badr);
    }
#pragma unroll
    for (int a = 0; a < 4; ++a)
#pragma unroll
      for (int b = 0; b < 4; ++b) {
        acc[a][b] = mfma16(fah[a], fbh[b], acc[a][b]);
        acc[a][b] = mfma16(fah[a], fbl[b], acc[a][b]);
        acc[a][b] = mfma16(fal[a], fbh[b], acc[a][b]);
      }
    __syncthreads();
  }

  // epilogue: +bias, RNE split, LDS-staged coalesced writes of hp rows.
#pragma unroll
  for (int a = 0; a < 4; ++a) {
    __syncthreads();
#pragma unroll
    for (int b = 0; b < 4; ++b) {
      int cloc = wc * 64 + b * 16 + l15;
      float bv = bias[n0 + cloc];
#pragma unroll
      for (int r = 0; r < 4; ++r) {
        int rloc = wr * 16 + 4 * l4 + r;
        float v = acc[a][b][r] + bv;
        unsigned short hh = f32_to_bf16(v);
        Ah[rloc * 128 + cloc] = hh;
        Al[rloc * 128 + cloc] = f32_to_bf16(v - bf16_to_f32(hh));
      }
    }
    __syncthreads();
    int rr = tid >> 3, c16 = (tid & 7) * 16;
    int mg = m0 + (rr >> 4) * 64 + a * 16 + (rr & 15);
    bf16x8 vh0 = *(const bf16x8*)(Ah + rr * 128 + c16);
    bf16x8 vh1 = *(const bf16x8*)(Ah + rr * 128 + c16 + 8);
    bf16x8 vl0 = *(const bf16x8*)(Al + rr * 128 + c16);
    bf16x8 vl1 = *(const bf16x8*)(Al + rr * 128 + c16 + 8);
    *(bf16x8*)(hp_hi + (size_t)mg * 512 + n0 + c16) = vh0;
    *(bf16x8*)(hp_hi + (size_t)mg * 512 + n0 + c16 + 8) = vh1;
    *(bf16x8*)(hp_lo + (size_t)mg * 512 + n0 + c16) = vl0;
    *(bf16x8*)(hp_lo + (size_t)mg * 512 + n0 + c16 + 8) = vl1;
  }
}

// ---------------------------------------------------------------------------
// Kernel 5: flash attention.  Block = (b, head, q-tile of 64), 4 waves x 16 q.
// K staged ONCE per kv-tile via GLD16; Vt built from K_lds by in-LDS
// transpose.  Swapped QK^T + pi-PV with P in registers.  Coalesced O writes.
// LDS padded to 56KB: hard cap 2 blocks/CU so the per-XCD working set
// (8 heads x 256KB K + 1MB adj) fits the 4MB XCD L2 (round-2-proven regime).
// ---------------------------------------------------------------------------
__global__ __launch_bounds__(256, 2) void attn_kernel(
    const unsigned short* __restrict__ hp_hi, const unsigned short* __restrict__ hp_lo,
    const float* __restrict__ adj, float* __restrict__ out) {
  int bid = blockIdx.x;
  int swz = (bid & 7) * 256 + (bid >> 3);       // 8 q-tiles of one (b,h) per XCD
  int qt = swz & 7;
  int hd = (swz >> 3) & 3;
  int bb = swz >> 5;
  int q0 = qt * 64;

  __shared__ alignas(16) unsigned short SM[28672];     // 56 KB (occupancy cap)
  unsigned short* K_hi  = SM;            // [32][128] swizzled
  unsigned short* K_lo  = SM + 4096;
  unsigned short* Vt_hi = SM + 8192;     // [128][32] swizzled
  unsigned short* Vt_lo = SM + 12288;

  int tid = threadIdx.x, w = tid >> 6, lane = tid & 63;
  int l15 = lane & 15, l4 = lane >> 4;
  int qg = q0 + w * 16 + l15;                   // this lane's softmax q row

  // Q fragments (B-operand: n=q at l&15, k=d contiguous), hi+lo, in registers
  bf16x8 qh[4], ql[4];
  {
    size_t base = ((size_t)bb * 512 + qg) * 512 + hd * 128 + 8 * l4;
#pragma unroll
    for (int ds = 0; ds < 4; ++ds) {
      qh[ds] = *(const bf16x8*)(hp_hi + base + ds * 32);
      ql[ds] = *(const bf16x8*)(hp_lo + base + ds * 32);
    }
  }

  f32x4 o[8];
#pragma unroll
  for (int vf = 0; vf < 8; ++vf) o[vf] = (f32x4){0.f, 0.f, 0.f, 0.f};
  float m_run = -3.0e38f, l_run = 0.f;

  // K staging role: w0: K_hi j0-3, w1: K_hi j4-7, w2: K_lo j0-3, w3: K_lo j4-7
  const unsigned short* ksb = (w & 2) ? hp_lo : hp_hi;
  unsigned short* kdb = (w & 2) ? K_lo : K_hi;
  int jbase = (w & 1) * 4;
  // Vt transpose role: w0: Vt_hi hf0, w1: Vt_hi hf1, w2: Vt_lo hf0, w3: Vt_lo hf1
  const unsigned short* tK = (w & 2) ? K_lo : K_hi;
  unsigned short* tV = (w & 2) ? Vt_lo : Vt_hi;
  int hf = w & 1;
  int kvg = lane >> 3, dg = lane & 7;           // transpose coords

  for (int t = 0; t < 16; ++t) {
    int kv0 = t * 32;
    // ---- stage K tile (hi+lo) via GLD16, 4 insts per wave
    {
      int kvl = lane >> 4, off = (lane & 15) * 16;
#pragma unroll
      for (int j2 = 0; j2 < 4; ++j2) {
        int j = jbase + j2;
        int kvr = j * 4 + kvl;
        const char* src = (const char*)ksb +
            (((size_t)(bb * 512 + kv0 + kvr)) * 512 + hd * 128) * 2 +
            (off ^ ((kvr & 7) << 4));
        GLD16(src, kdb + j * 512);
      }
    }
    // adj loads issued before the barrier (latency hidden under stage wait)
    f32x4 av0 = *(const f32x4*)(adj + (size_t)qg * 512 + kv0 + 4 * l4);
    f32x4 av1 = *(const f32x4*)(adj + (size_t)qg * 512 + kv0 + 16 + 4 * l4);
    __syncthreads();                            // K_lds ready

    // ---- build Vt quarter from K_lds (in-LDS transpose via registers)
    {
      bf16x8 L[4];
#pragma unroll
      for (int rr = 0; rr < 4; ++rr) {
        int kvr = kvg * 4 + rr;
        L[rr] = *(const bf16x8*)((const char*)tK + kvr * 256 +
                                 ((dg * 32 + hf * 16) ^ ((kvr & 7) << 4)));
      }
#pragma unroll
      for (int e = 0; e < 8; ++e) {
        int d = dg * 16 + hf * 8 + e;
        int vsw = ((((d >> 1) & 3) ^ ((d >> 4) & 3)) << 4);
        uint2 pk;
        pk.x = ((unsigned)(unsigned short)L[0][e]) |
               (((unsigned)(unsigned short)L[1][e]) << 16);
        pk.y = ((unsigned)(unsigned short)L[2][e]) |
               (((unsigned)(unsigned short)L[3][e]) << 16);
        *(uint2*)((char*)tV + d * 64 + ((kvg * 8) ^ vsw)) = pk;
      }
    }

    // ---- scores = K @ Q^T (swapped): lane q=l15, kv = {4*l4+r, 16+4*l4+r}
    f32x4 sc0 = {0.f, 0.f, 0.f, 0.f}, sc1 = {0.f, 0.f, 0.f, 0.f};
#pragma unroll
    for (int ds = 0; ds < 4; ++ds) {
      int kb = (ds * 32 + 8 * l4) * 2;
      int r0 = l15, r1 = 16 + l15;
      int a0 = r0 * 256 + (kb ^ ((r0 & 7) << 4));
      int a1 = r1 * 256 + (kb ^ ((r1 & 7) << 4));
      bf16x8 kh0 = *(const bf16x8*)((const char*)K_hi + a0);
      bf16x8 kl0 = *(const bf16x8*)((const char*)K_lo + a0);
      bf16x8 kh1 = *(const bf16x8*)((const char*)K_hi + a1);
      bf16x8 kl1 = *(const bf16x8*)((const char*)K_lo + a1);
      sc0 = mfma16(kh0, qh[ds], sc0); sc1 = mfma16(kh1, qh[ds], sc1);
      sc0 = mfma16(kh0, ql[ds], sc0); sc1 = mfma16(kh1, ql[ds], sc1);
      sc0 = mfma16(kl0, qh[ds], sc0); sc1 = mfma16(kl1, qh[ds], sc1);
    }

    // ---- adj multiply + online softmax (row q = l15; kv in-lane)
    float p0[4], p1[4];
    float tm = -3.0e38f;
#pragma unroll
    for (int r = 0; r < 4; ++r) {
      p0[r] = sc0[r] * av0[r];
      p1[r] = sc1[r] * av1[r];
      tm = fmaxf(tm, fmaxf(p0[r], p1[r]));
    }
    tm = fmaxf(tm, __shfl_xor(tm, 16));
    tm = fmaxf(tm, __shfl_xor(tm, 32));
    if (__any(tm > m_run + 8.0f)) {             // T13 defer-rescale
      float mn = fmaxf(m_run, tm);
      float scl = __expf(m_run - mn);
      m_run = mn;
      l_run *= scl;
      f32x4 s4;
#pragma unroll
      for (int r = 0; r < 4; ++r) s4[r] = bperm_f(4 * l4 + r, scl);
#pragma unroll
      for (int vf = 0; vf < 8; ++vf)
#pragma unroll
        for (int r = 0; r < 4; ++r) o[vf][r] *= s4[r];
    }
    float ps = 0.f;
#pragma unroll
    for (int r = 0; r < 4; ++r) {
      p0[r] = __expf(p0[r] - m_run); ps += p0[r];
      p1[r] = __expf(p1[r] - m_run); ps += p1[r];
    }
    ps += __shfl_xor(ps, 16);
    ps += __shfl_xor(ps, 32);
    l_run += ps;

    // ---- pack P in-lane: A-frag slots e = {p0[0..3], p1[0..3]} (pi order)
    union PU { bf16x8 v; unsigned u[4]; } pah, pal;
#pragma unroll
    for (int i = 0; i < 4; ++i) {
      float fa = (i < 2) ? p0[2 * i] : p1[2 * (i - 2)];
      float fb = (i < 2) ? p0[2 * i + 1] : p1[2 * (i - 2) + 1];
      unsigned ua = __float_as_uint(fa), ub = __float_as_uint(fb);
      pah.u[i] = (ua >> 16) | (ub & 0xFFFF0000u);
      float la = fa - __uint_as_float(ua & 0xFFFF0000u);
      float lb = fb - __uint_as_float(ub & 0xFFFF0000u);
      pal.u[i] = (__float_as_uint(la) >> 16) | (__float_as_uint(lb) & 0xFFFF0000u);
    }

    __syncthreads();                            // Vt ready; K reads done

    // ---- O += P @ V (3-term), V via 2x ds_read_b64 at pi k-slots
#pragma unroll
    for (int vf = 0; vf < 8; ++vf) {
      int d = vf * 16 + l15;
      int vsw = ((((d >> 1) & 3) ^ (vf & 3)) << 4);
      const char* bh = (const char*)Vt_hi + d * 64;
      const char* bl = (const char*)Vt_lo + d * 64;
      int o1 = (8 * l4) ^ vsw, o2 = (32 + 8 * l4) ^ vsw;
      union VU { bf16x8 v; uint2 u[2]; } vh, vl;
      vh.u[0] = *(const uint2*)(bh + o1); vh.u[1] = *(const uint2*)(bh + o2);
      vl.u[0] = *(const uint2*)(bl + o1); vl.u[1] = *(const uint2*)(bl + o2);
      o[vf] = mfma16(pah.v, vh.v, o[vf]);
      o[vf] = mfma16(pah.v, vl.v, o[vf]);
      o[vf] = mfma16(pal.v, vh.v, o[vf]);
    }
    // next iteration's GLD16 writes K only (PV stragglers read Vt only);
    // next iteration's barrier-1 gates Vt overwrite.  No trailing barrier.
  }

  // ---- epilogue: divide by row sums, stage O in LDS, coalesced f32 writes
  float rinv = 1.0f / l_run;
  f32x4 r4;
#pragma unroll
  for (int r = 0; r < 4; ++r) r4[r] = bperm_f(4 * l4 + r, rinv);
  __syncthreads();                              // all PV reads of SM done
  float* wbase = (float*)SM + w * 2048;         // [16][128] f32 per wave
#pragma unroll
  for (int vf = 0; vf < 8; ++vf)
#pragma unroll
    for (int r = 0; r < 4; ++r)
      wbase[(4 * l4 + r) * 128 + vf * 16 + l15] = o[vf][r] * r4[r];
  __syncthreads();                              // also fences the alias write
#pragma unroll
  for (int p = 0; p < 4; ++p) {
    int row = p * 4 + l4;
    f32x4 v0 = *(const f32x4*)(wbase + row * 128 + l15 * 8);
    f32x4 v1 = *(const f32x4*)(wbase + row * 128 + l15 * 8 + 4);
    size_t mg = (size_t)bb * 512 + q0 + w * 16 + row;
    float* op = out + mg * 512 + hd * 128 + l15 * 8;
    *(f32x4*)op = v0;
    *(f32x4*)(op + 4) = v1;
  }
}

// ---------------------------------------------------------------------------
// Kernel 6: LayerNorm (over C=512) + exact-erf GELU, in place on d_out.
// ---------------------------------------------------------------------------
__global__ __launch_bounds__(256) void ln_gelu_kernel(
    float* __restrict__ io, const float* __restrict__ gamma,
    const float* __restrict__ beta) {
  int w = threadIdx.x >> 6, lane = threadIdx.x & 63;
  size_t row = (size_t)blockIdx.x * 4 + w;
  float* p = io + row * 512;
  f32x4 x0 = *(const f32x4*)(p + lane * 8);
  f32x4 x1 = *(const f32x4*)(p + lane * 8 + 4);
  float s = x0[0] + x0[1] + x0[2] + x0[3] + x1[0] + x1[1] + x1[2] + x1[3];
#pragma unroll
  for (int off = 32; off >= 1; off >>= 1) s += __shfl_xor(s, off);
  float mu = s * (1.0f / 512.0f);
  float vs = 0.f;
#pragma unroll
  for (int e = 0; e < 4; ++e) {
    float d0 = x0[e] - mu; vs += d0 * d0;
    float d1 = x1[e] - mu; vs += d1 * d1;
  }
#pragma unroll
  for (int off = 32; off >= 1; off >>= 1) vs += __shfl_xor(vs, off);
  float rs = rsqrtf(vs * (1.0f / 512.0f) + 1e-5f);
  f32x4 g0 = *(const f32x4*)(gamma + lane * 8);
  f32x4 g1 = *(const f32x4*)(gamma + lane * 8 + 4);
  f32x4 b0 = *(const f32x4*)(beta + lane * 8);
  f32x4 b1 = *(const f32x4*)(beta + lane * 8 + 4);
  f32x4 y0, y1;
#pragma unroll
  for (int e = 0; e < 4; ++e) {
    float y = (x0[e] - mu) * rs * g0[e] + b0[e];
    y0[e] = 0.5f * y * (1.0f + erff(y * 0.70710678118654752f));
    float z = (x1[e] - mu) * rs * g1[e] + b1[e];
    y1[e] = 0.5f * z * (1.0f + erff(z * 0.70710678118654752f));
  }
  *(f32x4*)(p + lane * 8) = y0;
  *(f32x4*)(p + lane * 8 + 4) = y1;
}

// ---------------------------------------------------------------------------
// Host launcher.  Inputs: [0]=t [1]=h [2]=W [3]=b [4]=adj [5]=gamma [6]=beta
// Workspace (~135 MB):
//   h_hi   = ws + 0          (16.7M u16)
//   h_lo   = ws + 16777216
//   hp_hi  = ws + 33554432
//   hp_lo  = ws + 50331648
//   Wt_hi  = ws + 67108864   (262144 u16)
//   Wt_lo  = ws + 67371008
// ---------------------------------------------------------------------------
extern "C" void kernel_launch(void* const* d_in, const int* in_sizes, int n_in,
                              void* d_out, int out_size, void* d_ws, size_t ws_size,
                              hipStream_t stream) {
  const float* h     = (const float*)d_in[1];
  const float* W     = (const float*)d_in[2];
  const float* bias  = (const float*)d_in[3];
  const float* adj   = (const float*)d_in[4];
  const float* gamma = (const float*)d_in[5];
  const float* beta  = (const float*)d_in[6];
  float* out = (float*)d_out;

  unsigned short* ws = (unsigned short*)d_ws;
  unsigned short* h_hi   = ws;
  unsigned short* h_lo   = ws + 16777216;
  unsigned short* hp_hi  = ws + 33554432;
  unsigned short* hp_lo  = ws + 50331648;
  unsigned short* Wt_hi  = ws + 67108864;
  unsigned short* Wt_lo  = ws + 67371008;

  cast_split_h<<<8192, 256, 0, stream>>>(h, h_hi, h_lo);
  cast_split_Wt<<<1024, 256, 0, stream>>>(W, Wt_hi, Wt_lo);
  proj_gemm<<<1024, 256, 0, stream>>>(h_hi, h_lo, Wt_hi, Wt_lo, bias, hp_hi, hp_lo);
  attn_kernel<<<2048, 256, 0, stream>>>(hp_hi, hp_lo, adj, out);
  ln_gelu_kernel<<<8192, 256, 0, stream>>>(out, gamma, beta);
}

// Round 7
// 250.611 us; speedup vs baseline: 1.9214x; 1.1616x over previous
//
#include <hip/hip_runtime.h>
#include <stdint.h>

// ---------------------------------------------------------------------------
// GraphAttentionLayer fused pipeline, MI355X (gfx950)
// B=64 S=512 C=512 H=4 D=128.  Split-bf16 (hi+lo) 3-term MFMA for GEMM/QK^T.
// Round 7: attn K double-buffer pipeline (stage t+1 overlaps compute of t),
// PV single-term (P_full @ V_hi), conflict-free transpose (K_hi only, waves
// 0-1; waves 2-3 stage).  2 blocks/CU cap kept (the round-6 L2 regime).
// ---------------------------------------------------------------------------

typedef float  f32x4   __attribute__((ext_vector_type(4)));
typedef short  bf16x8  __attribute__((ext_vector_type(8)));
typedef unsigned short ushort8 __attribute__((ext_vector_type(8)));

#define GLD16(src, dst)                                                        \
  __builtin_amdgcn_global_load_lds(                                            \
      (const __attribute__((address_space(1))) void*)(src),                    \
      (__attribute__((address_space(3))) void*)(dst), 16, 0, 0)

__device__ __forceinline__ unsigned short f32_to_bf16(float x) {
  union { float f; unsigned int u; } v; v.f = x;
  unsigned int r = v.u + 0x7FFFu + ((v.u >> 16) & 1u);
  return (unsigned short)(r >> 16);
}
__device__ __forceinline__ float bf16_to_f32(unsigned short h) {
  union { float f; unsigned int u; } v; v.u = ((unsigned int)h) << 16;
  return v.f;
}
__device__ __forceinline__ f32x4 mfma16(bf16x8 a, bf16x8 b, f32x4 c) {
  return __builtin_amdgcn_mfma_f32_16x16x32_bf16(a, b, c, 0, 0, 0);
}
__device__ __forceinline__ float bperm_f(int srcLane, float v) {
  return __int_as_float(__builtin_amdgcn_ds_bpermute(srcLane << 2, __float_as_int(v)));
}

// ---------------------------------------------------------------------------
// Kernel 1: split h (fp32) -> h_hi, h_lo (bf16).  8 elems/thread.
// ---------------------------------------------------------------------------
__global__ __launch_bounds__(256) void cast_split_h(
    const float* __restrict__ src, unsigned short* __restrict__ dhi,
    unsigned short* __restrict__ dlo) {
  size_t i = ((size_t)blockIdx.x * 256 + threadIdx.x) * 8;
  f32x4 a = *(const f32x4*)(src + i);
  f32x4 b = *(const f32x4*)(src + i + 4);
  ushort8 hi, lo;
#pragma unroll
  for (int e = 0; e < 4; ++e) {
    unsigned short h0 = f32_to_bf16(a[e]);
    hi[e] = h0; lo[e] = f32_to_bf16(a[e] - bf16_to_f32(h0));
    unsigned short h1 = f32_to_bf16(b[e]);
    hi[4 + e] = h1; lo[4 + e] = f32_to_bf16(b[e] - bf16_to_f32(h1));
  }
  *(ushort8*)(dhi + i) = hi;
  *(ushort8*)(dlo + i) = lo;
}

// ---------------------------------------------------------------------------
// Kernel 2: W [H,C,D] fp32 -> Wt_hi/lo [H,D,C] bf16 (transposed per head).
// ---------------------------------------------------------------------------
__global__ __launch_bounds__(256) void cast_split_Wt(
    const float* __restrict__ W, unsigned short* __restrict__ whi,
    unsigned short* __restrict__ wlo) {
  int o = blockIdx.x * 256 + threadIdx.x;      // [0, 4*128*512)
  int hd = o >> 16;                             // head
  int rem = o & 65535;
  int d = rem >> 9;                             // [0,128)
  int c = rem & 511;                            // [0,512)
  float v = W[((size_t)(hd * 512 + c)) * 128 + d];
  unsigned short h0 = f32_to_bf16(v);
  whi[o] = h0;
  wlo[o] = f32_to_bf16(v - bf16_to_f32(h0));
}

// ---------------------------------------------------------------------------
// Kernel 3: projection GEMM  hp = h @ Wall + bias   ([32768x512]@[512x512])
// split-bf16 3-term.  128x128 tile, BK=32, 4 waves (2x2), 16x16x32 MFMA.
// Epilogue: stage through LDS (reuse Ah/Al), write hp [b*512+s][c] coalesced.
// ---------------------------------------------------------------------------
__global__ __launch_bounds__(256, 2) void proj_gemm(
    const unsigned short* __restrict__ ahi, const unsigned short* __restrict__ alo,
    const unsigned short* __restrict__ whi, const unsigned short* __restrict__ wlo,
    const float* __restrict__ bias, unsigned short* __restrict__ hp_hi,
    unsigned short* __restrict__ hp_lo) {
  int bid = blockIdx.x;
  int swz = (bid & 7) * 128 + (bid >> 3);       // XCD-contiguous work chunks
  int nt = swz & 3, mt = swz >> 2;
  int m0 = mt * 128, n0 = nt * 128;             // n-tile == head nt

  __shared__ alignas(16) unsigned short Ah[128 * 32], Al[128 * 32];
  __shared__ alignas(16) unsigned short Bh[128 * 32], Bl[128 * 32];

  int tid = threadIdx.x, wv = tid >> 6, lane = tid & 63;
  int l15 = lane & 15, l4 = lane >> 4;
  int wr = wv >> 1, wc = wv & 1;

  f32x4 acc[4][4];
#pragma unroll
  for (int a = 0; a < 4; ++a)
#pragma unroll
    for (int b = 0; b < 4; ++b) acc[a][b] = (f32x4){0.f, 0.f, 0.f, 0.f};

  for (int ks = 0; ks < 16; ++ks) {
    int k0 = ks * 32;
    for (int i = wv; i < 32; i += 4) {
      int grp = i >> 3, j = i & 7;
      int row = j * 16 + (lane >> 2);
      int off = (lane & 3) * 16;
      int sw = ((row >> 1) & 3) << 4;
      const unsigned short* sb;
      unsigned short* db;
      size_t srcoff;
      if (grp == 0)      { sb = ahi; db = Ah; srcoff = ((size_t)(m0 + row) * 512 + k0) * 2; }
      else if (grp == 1) { sb = alo; db = Al; srcoff = ((size_t)(m0 + row) * 512 + k0) * 2; }
      else if (grp == 2) { sb = whi; db = Bh; srcoff = ((size_t)(nt * 128 + row) * 512 + k0) * 2; }
      else               { sb = wlo; db = Bl; srcoff = ((size_t)(nt * 128 + row) * 512 + k0) * 2; }
      GLD16((const char*)sb + srcoff + (off ^ sw), db + j * 512);
    }
    __syncthreads();

    bf16x8 fah[4], fal[4], fbh[4], fbl[4];
#pragma unroll
    for (int f = 0; f < 4; ++f) {
      int mr = wr * 64 + f * 16 + l15;
      int aadr = mr * 64 + ((16 * l4) ^ (((mr >> 1) & 3) << 4));
      fah[f] = *(const bf16x8*)((const char*)Ah + aadr);
      fal[f] = *(const bf16x8*)((const char*)Al + aadr);
      int nr = wc * 64 + f * 16 + l15;
      int badr = nr * 64 + ((16 * l4) ^ (((nr >> 1) & 3) << 4));
      fbh[f] = *(const bf16x8*)((const char*)Bh + badr);
      fbl[f] = *(const bf16x8*)((const char*)Bl + badr);
    }
#pragma unroll
    for (int a = 0; a < 4; ++a)
#pragma unroll
      for (int b = 0; b < 4; ++b) {
        acc[a][b] = mfma16(fah[a], fbh[b], acc[a][b]);
        acc[a][b] = mfma16(fah[a], fbl[b], acc[a][b]);
        acc[a][b] = mfma16(fal[a], fbh[b], acc[a][b]);
      }
    __syncthreads();
  }

  // epilogue: +bias, RNE split, LDS-staged coalesced writes of hp rows.
#pragma unroll
  for (int a = 0; a < 4; ++a) {
    __syncthreads();
#pragma unroll
    for (int b = 0; b < 4; ++b) {
      int cloc = wc * 64 + b * 16 + l15;
      float bv = bias[n0 + cloc];
#pragma unroll
      for (int r = 0; r < 4; ++r) {
        int rloc = wr * 16 + 4 * l4 + r;
        float v = acc[a][b][r] + bv;
        unsigned short hh = f32_to_bf16(v);
        Ah[rloc * 128 + cloc] = hh;
        Al[rloc * 128 + cloc] = f32_to_bf16(v - bf16_to_f32(hh));
      }
    }
    __syncthreads();
    int rr = tid >> 3, c16 = (tid & 7) * 16;
    int mg = m0 + (rr >> 4) * 64 + a * 16 + (rr & 15);
    bf16x8 vh0 = *(const bf16x8*)(Ah + rr * 128 + c16);
    bf16x8 vh1 = *(const bf16x8*)(Ah + rr * 128 + c16 + 8);
    bf16x8 vl0 = *(const bf16x8*)(Al + rr * 128 + c16);
    bf16x8 vl1 = *(const bf16x8*)(Al + rr * 128 + c16 + 8);
    *(bf16x8*)(hp_hi + (size_t)mg * 512 + n0 + c16) = vh0;
    *(bf16x8*)(hp_hi + (size_t)mg * 512 + n0 + c16 + 8) = vh1;
    *(bf16x8*)(hp_lo + (size_t)mg * 512 + n0 + c16) = vl0;
    *(bf16x8*)(hp_lo + (size_t)mg * 512 + n0 + c16 + 8) = vl1;
  }
}

// ---------------------------------------------------------------------------
// Kernel 5: flash attention.  Block = (b, head, q-tile of 64), 4 waves x 16 q.
// K double-buffered: waves 2-3 stage K[t+1] (GLD16) at tile-t top, overlapping
// waves 0-1's K_hi->Vt transpose + everyone's QK^T/softmax.  PV single-term
// (full-P @ V_hi).  Swapped QK^T + pi-permuted PV, P in registers.
// LDS: K dbuf 2x16KB + Vt 8KB, padded to 56KB (2 blocks/CU L2-regime cap).
// ---------------------------------------------------------------------------
__global__ __launch_bounds__(256, 2) void attn_kernel(
    const unsigned short* __restrict__ hp_hi, const unsigned short* __restrict__ hp_lo,
    const float* __restrict__ adj, float* __restrict__ out) {
  int bid = blockIdx.x;
  int swz = (bid & 7) * 256 + (bid >> 3);       // 8 q-tiles of one (b,h) per XCD
  int qt = swz & 7;
  int hd = (swz >> 3) & 3;
  int bb = swz >> 5;
  int q0 = qt * 64;

  __shared__ alignas(16) unsigned short SM[28672];     // 56 KB (occupancy cap)
  // layout (u16 offsets): buf0 K_hi@0 K_lo@4096; buf1 K_hi@8192 K_lo@12288;
  // Vt_hi@16384 ([128][32] swizzled)

  int tid = threadIdx.x, w = tid >> 6, lane = tid & 63;
  int l15 = lane & 15, l4 = lane >> 4;
  int qg = q0 + w * 16 + l15;                   // this lane's softmax q row

  // Q fragments (B-operand: n=q at l&15, k=d contiguous), hi+lo, in registers
  bf16x8 qh[4], ql[4];
  {
    size_t base = ((size_t)bb * 512 + qg) * 512 + hd * 128 + 8 * l4;
#pragma unroll
    for (int ds = 0; ds < 4; ++ds) {
      qh[ds] = *(const bf16x8*)(hp_hi + base + ds * 32);
      ql[ds] = *(const bf16x8*)(hp_lo + base + ds * 32);
    }
  }

  f32x4 o[8];
#pragma unroll
  for (int vf = 0; vf < 8; ++vf) o[vf] = (f32x4){0.f, 0.f, 0.f, 0.f};
  float m_run = -3.0e38f, l_run = 0.f;

  int kvl = lane >> 4, soff = (lane & 15) * 16; // K staging coords
  int kvg = lane >> 3, dg = lane & 7;           // transpose coords
  unsigned short* Vt = SM + 16384;

  // ---- prologue: all 4 waves stage K[0] into buf0
  {
    const unsigned short* sb = (w & 2) ? hp_lo : hp_hi;
    unsigned short* db = SM + (w & 2) * 2048;   // w0,1 -> 0 ; w2,3 -> 4096
    int jbase = (w & 1) * 4;
#pragma unroll
    for (int j2 = 0; j2 < 4; ++j2) {
      int j = jbase + j2;
      int kvr = j * 4 + kvl;
      const char* src = (const char*)sb +
          (((size_t)(bb * 512 + kvr)) * 512 + hd * 128) * 2 +
          (soff ^ ((kvr & 7) << 4));
      GLD16(src, db + j * 512);
    }
  }
  __syncthreads();

  for (int t = 0; t < 16; ++t) {
    int kv0 = t * 32;
    unsigned short* Kb = SM + ((t & 1) << 13);  // current K buffer (16KB)
    unsigned short* K_hi = Kb;
    unsigned short* K_lo = Kb + 4096;

    // ---- waves 2-3: stage K[t+1] into the other buffer (overlaps compute)
    if (w >= 2 && t < 15) {
      int kv1 = kv0 + 32;
      const unsigned short* sb = (w == 2) ? hp_hi : hp_lo;
      unsigned short* db = SM + (((t + 1) & 1) << 13) + (w == 3) * 4096;
#pragma unroll
      for (int j = 0; j < 8; ++j) {
        int kvr = j * 4 + kvl;
        const char* src = (const char*)sb +
            (((size_t)(bb * 512 + kv1 + kvr)) * 512 + hd * 128) * 2 +
            (soff ^ ((kvr & 7) << 4));
        GLD16(src, db + j * 512);
      }
    }
    // adj loads early (latency hidden under compute)
    f32x4 av0 = *(const f32x4*)(adj + (size_t)qg * 512 + kv0 + 4 * l4);
    f32x4 av1 = *(const f32x4*)(adj + (size_t)qg * 512 + kv0 + 16 + 4 * l4);

    // ---- waves 0-1: transpose K_hi -> Vt (conflict-free read mapping)
    if (w < 2) {
      bf16x8 L[4];
#pragma unroll
      for (int rr = 0; rr < 4; ++rr) {
        int kvr = kvg * 4 + rr;
        L[rr] = *(const bf16x8*)((const char*)K_hi + kvr * 256 +
                                 ((w * 128 + dg * 16) ^ ((kvr & 7) << 4)));
      }
#pragma unroll
      for (int e = 0; e < 8; ++e) {
        int d = w * 64 + dg * 8 + e;
        int vsw = ((((d >> 1) & 3) ^ ((d >> 4) & 3)) << 4);
        uint2 pk;
        pk.x = ((unsigned)(unsigned short)L[0][e]) |
               (((unsigned)(unsigned short)L[1][e]) << 16);
        pk.y = ((unsigned)(unsigned short)L[2][e]) |
               (((unsigned)(unsigned short)L[3][e]) << 16);
        *(uint2*)((char*)Vt + d * 64 + ((kvg * 8) ^ vsw)) = pk;
      }
    }

    // ---- scores = K @ Q^T (swapped): lane q=l15, kv = {4*l4+r, 16+4*l4+r}
    f32x4 sc0 = {0.f, 0.f, 0.f, 0.f}, sc1 = {0.f, 0.f, 0.f, 0.f};
#pragma unroll
    for (int ds = 0; ds < 4; ++ds) {
      int kb = (ds * 32 + 8 * l4) * 2;
      int r0 = l15, r1 = 16 + l15;
      int a0 = r0 * 256 + (kb ^ ((r0 & 7) << 4));
      int a1 = r1 * 256 + (kb ^ ((r1 & 7) << 4));
      bf16x8 kh0 = *(const bf16x8*)((const char*)K_hi + a0);
      bf16x8 kl0 = *(const bf16x8*)((const char*)K_lo + a0);
      bf16x8 kh1 = *(const bf16x8*)((const char*)K_hi + a1);
      bf16x8 kl1 = *(const bf16x8*)((const char*)K_lo + a1);
      sc0 = mfma16(kh0, qh[ds], sc0); sc1 = mfma16(kh1, qh[ds], sc1);
      sc0 = mfma16(kh0, ql[ds], sc0); sc1 = mfma16(kh1, ql[ds], sc1);
      sc0 = mfma16(kl0, qh[ds], sc0); sc1 = mfma16(kl1, qh[ds], sc1);
    }

    // ---- adj multiply + online softmax (row q = l15; kv in-lane)
    float p0[4], p1[4];
    float tm = -3.0e38f;
#pragma unroll
    for (int r = 0; r < 4; ++r) {
      p0[r] = sc0[r] * av0[r];
      p1[r] = sc1[r] * av1[r];
      tm = fmaxf(tm, fmaxf(p0[r], p1[r]));
    }
    tm = fmaxf(tm, __shfl_xor(tm, 16));
    tm = fmaxf(tm, __shfl_xor(tm, 32));
    if (__any(tm > m_run + 8.0f)) {             // T13 defer-rescale
      float mn = fmaxf(m_run, tm);
      float scl = __expf(m_run - mn);
      m_run = mn;
      l_run *= scl;
      f32x4 s4;
#pragma unroll
      for (int r = 0; r < 4; ++r) s4[r] = bperm_f(4 * l4 + r, scl);
#pragma unroll
      for (int vf = 0; vf < 8; ++vf)
#pragma unroll
        for (int r = 0; r < 4; ++r) o[vf][r] *= s4[r];
    }
    float ps = 0.f;
#pragma unroll
    for (int r = 0; r < 4; ++r) {
      p0[r] = __expf(p0[r] - m_run); ps += p0[r];
      p1[r] = __expf(p1[r] - m_run); ps += p1[r];
    }
    ps += __shfl_xor(ps, 16);
    ps += __shfl_xor(ps, 32);
    l_run += ps;

    // ---- pack P (trunc hi + residual lo) into pi-ordered A-frags
    union PU { bf16x8 v; unsigned u[4]; } pah, pal;
#pragma unroll
    for (int i = 0; i < 4; ++i) {
      float fa = (i < 2) ? p0[2 * i] : p1[2 * (i - 2)];
      float fb = (i < 2) ? p0[2 * i + 1] : p1[2 * (i - 2) + 1];
      unsigned ua = __float_as_uint(fa), ub = __float_as_uint(fb);
      pah.u[i] = (ua >> 16) | (ub & 0xFFFF0000u);
      float la = fa - __uint_as_float(ua & 0xFFFF0000u);
      float lb = fb - __uint_as_float(ub & 0xFFFF0000u);
      pal.u[i] = (__float_as_uint(la) >> 16) | (__float_as_uint(lb) & 0xFFFF0000u);
    }

    __syncthreads();   // Vt ready; K[t+1] GLD16s drained (overlapped issue)

    // ---- O += P @ V_hi (2 mfma/vf: full-P x bf16-V), V via 2x ds_read_b64
#pragma unroll
    for (int vf = 0; vf < 8; ++vf) {
      int d = vf * 16 + l15;
      int vsw = ((((d >> 1) & 3) ^ (vf & 3)) << 4);
      const char* bh = (const char*)Vt + d * 64;
      int o1 = (8 * l4) ^ vsw, o2 = (32 + 8 * l4) ^ vsw;
      union VU { bf16x8 v; uint2 u[2]; } vh;
      vh.u[0] = *(const uint2*)(bh + o1); vh.u[1] = *(const uint2*)(bh + o2);
      o[vf] = mfma16(pah.v, vh.v, o[vf]);
      o[vf] = mfma16(pal.v, vh.v, o[vf]);
    }
    __syncthreads();   // PV done: next tile may overwrite Vt and K[t&1]
  }

  // ---- epilogue: divide by row sums, stage O in LDS, coalesced f32 writes
  float rinv = 1.0f / l_run;
  f32x4 r4;
#pragma unroll
  for (int r = 0; r < 4; ++r) r4[r] = bperm_f(4 * l4 + r, rinv);
  float* wbase = (float*)SM + w * 2048;         // [16][128] f32 per wave
#pragma unroll
  for (int vf = 0; vf < 8; ++vf)
#pragma unroll
    for (int r = 0; r < 4; ++r)
      wbase[(4 * l4 + r) * 128 + vf * 16 + l15] = o[vf][r] * r4[r];
  __syncthreads();
#pragma unroll
  for (int p = 0; p < 4; ++p) {
    int row = p * 4 + l4;
    f32x4 v0 = *(const f32x4*)(wbase + row * 128 + l15 * 8);
    f32x4 v1 = *(const f32x4*)(wbase + row * 128 + l15 * 8 + 4);
    size_t mg = (size_t)bb * 512 + q0 + w * 16 + row;
    float* op = out + mg * 512 + hd * 128 + l15 * 8;
    *(f32x4*)op = v0;
    *(f32x4*)(op + 4) = v1;
  }
}

// ---------------------------------------------------------------------------
// Kernel 6: LayerNorm (over C=512) + exact-erf GELU, in place on d_out.
// ---------------------------------------------------------------------------
__global__ __launch_bounds__(256) void ln_gelu_kernel(
    float* __restrict__ io, const float* __restrict__ gamma,
    const float* __restrict__ beta) {
  int w = threadIdx.x >> 6, lane = threadIdx.x & 63;
  size_t row = (size_t)blockIdx.x * 4 + w;
  float* p = io + row * 512;
  f32x4 x0 = *(const f32x4*)(p + lane * 8);
  f32x4 x1 = *(const f32x4*)(p + lane * 8 + 4);
  float s = x0[0] + x0[1] + x0[2] + x0[3] + x1[0] + x1[1] + x1[2] + x1[3];
#pragma unroll
  for (int off = 32; off >= 1; off >>= 1) s += __shfl_xor(s, off);
  float mu = s * (1.0f / 512.0f);
  float vs = 0.f;
#pragma unroll
  for (int e = 0; e < 4; ++e) {
    float d0 = x0[e] - mu; vs += d0 * d0;
    float d1 = x1[e] - mu; vs += d1 * d1;
  }
#pragma unroll
  for (int off = 32; off >= 1; off >>= 1) vs += __shfl_xor(vs, off);
  float rs = rsqrtf(vs * (1.0f / 512.0f) + 1e-5f);
  f32x4 g0 = *(const f32x4*)(gamma + lane * 8);
  f32x4 g1 = *(const f32x4*)(gamma + lane * 8 + 4);
  f32x4 b0 = *(const f32x4*)(beta + lane * 8);
  f32x4 b1 = *(const f32x4*)(beta + lane * 8 + 4);
  f32x4 y0, y1;
#pragma unroll
  for (int e = 0; e < 4; ++e) {
    float y = (x0[e] - mu) * rs * g0[e] + b0[e];
    y0[e] = 0.5f * y * (1.0f + erff(y * 0.70710678118654752f));
    float z = (x1[e] - mu) * rs * g1[e] + b1[e];
    y1[e] = 0.5f * z * (1.0f + erff(z * 0.70710678118654752f));
  }
  *(f32x4*)(p + lane * 8) = y0;
  *(f32x4*)(p + lane * 8 + 4) = y1;
}

// ---------------------------------------------------------------------------
// Host launcher.  Inputs: [0]=t [1]=h [2]=W [3]=b [4]=adj [5]=gamma [6]=beta
// Workspace (~135 MB):
//   h_hi   = ws + 0          (16.7M u16)
//   h_lo   = ws + 16777216
//   hp_hi  = ws + 33554432
//   hp_lo  = ws + 50331648
//   Wt_hi  = ws + 67108864   (262144 u16)
//   Wt_lo  = ws + 67371008
// ---------------------------------------------------------------------------
extern "C" void kernel_launch(void* const* d_in, const int* in_sizes, int n_in,
                              void* d_out, int out_size, void* d_ws, size_t ws_size,
                              hipStream_t stream) {
  const float* h     = (const float*)d_in[1];
  const float* W     = (const float*)d_in[2];
  const float* bias  = (const float*)d_in[3];
  const float* adj   = (const float*)d_in[4];
  const float* gamma = (const float*)d_in[5];
  const float* beta  = (const float*)d_in[6];
  float* out = (float*)d_out;

  unsigned short* ws = (unsigned short*)d_ws;
  unsigned short* h_hi   = ws;
  unsigned short* h_lo   = ws + 16777216;
  unsigned short* hp_hi  = ws + 33554432;
  unsigned short* hp_lo  = ws + 50331648;
  unsigned short* Wt_hi  = ws + 67108864;
  unsigned short* Wt_lo  = ws + 67371008;

  cast_split_h<<<8192, 256, 0, stream>>>(h, h_hi, h_lo);
  cast_split_Wt<<<1024, 256, 0, stream>>>(W, Wt_hi, Wt_lo);
  proj_gemm<<<1024, 256, 0, stream>>>(h_hi, h_lo, Wt_hi, Wt_lo, bias, hp_hi, hp_lo);
  attn_kernel<<<2048, 256, 0, stream>>>(hp_hi, hp_lo, adj, out);
  ln_gelu_kernel<<<8192, 256, 0, stream>>>(out, gamma, beta);
}

// Round 9
// 225.307 us; speedup vs baseline: 2.1372x; 1.1123x over previous
//
#include <hip/hip_runtime.h>
#include <stdint.h>

// ---------------------------------------------------------------------------
// GraphAttentionLayer fused pipeline, MI355X (gfx950)
// B=64 S=512 C=512 H=4 D=128.  Split-bf16 (hi+lo) 3-term MFMA for GEMM/QK^T.
// Round 9: round-8 structure with the tr_read addressing FIXED — per-lane
// canonical b64 address (base + lane*8B) per m156/m162; uniform base reads
// the same value in all lanes (that was the round-8 bug).
// K subtiled [8 sd][32 kv][16 d], double-buffered, one barrier per tile.
// ---------------------------------------------------------------------------

typedef float  f32x4   __attribute__((ext_vector_type(4)));
typedef short  bf16x8  __attribute__((ext_vector_type(8)));
typedef unsigned short ushort8 __attribute__((ext_vector_type(8)));
typedef unsigned int   uint2v  __attribute__((ext_vector_type(2)));

#define GLD16(src, dst)                                                        \
  __builtin_amdgcn_global_load_lds(                                            \
      (const __attribute__((address_space(1))) void*)(src),                    \
      (__attribute__((address_space(3))) void*)(dst), 16, 0, 0)

__device__ __forceinline__ unsigned short f32_to_bf16(float x) {
  union { float f; unsigned int u; } v; v.f = x;
  unsigned int r = v.u + 0x7FFFu + ((v.u >> 16) & 1u);
  return (unsigned short)(r >> 16);
}
__device__ __forceinline__ float bf16_to_f32(unsigned short h) {
  union { float f; unsigned int u; } v; v.u = ((unsigned int)h) << 16;
  return v.f;
}
__device__ __forceinline__ f32x4 mfma16(bf16x8 a, bf16x8 b, f32x4 c) {
  return __builtin_amdgcn_mfma_f32_16x16x32_bf16(a, b, c, 0, 0, 0);
}
__device__ __forceinline__ float bperm_f(int srcLane, float v) {
  return __int_as_float(__builtin_amdgcn_ds_bpermute(srcLane << 2, __float_as_int(v)));
}
// HW transpose read.  Address must be the canonical per-lane b64 address
// (base + lane*8B).  Lane l elem j <- lds_bf16[base + (l&15) + j*16 + (l>>4)*64].
__device__ __forceinline__ uint2v tr_read(const unsigned short* p) {
  uint2v r;
  asm volatile("ds_read_b64_tr_b16 %0, %1"
               : "=v"(r)
               : "v"((const __attribute__((address_space(3))) void*)p));
  return r;
}

// ---------------------------------------------------------------------------
// Kernel 1: split h (fp32) -> h_hi, h_lo (bf16).  8 elems/thread.
// ---------------------------------------------------------------------------
__global__ __launch_bounds__(256) void cast_split_h(
    const float* __restrict__ src, unsigned short* __restrict__ dhi,
    unsigned short* __restrict__ dlo) {
  size_t i = ((size_t)blockIdx.x * 256 + threadIdx.x) * 8;
  f32x4 a = *(const f32x4*)(src + i);
  f32x4 b = *(const f32x4*)(src + i + 4);
  ushort8 hi, lo;
#pragma unroll
  for (int e = 0; e < 4; ++e) {
    unsigned short h0 = f32_to_bf16(a[e]);
    hi[e] = h0; lo[e] = f32_to_bf16(a[e] - bf16_to_f32(h0));
    unsigned short h1 = f32_to_bf16(b[e]);
    hi[4 + e] = h1; lo[4 + e] = f32_to_bf16(b[e] - bf16_to_f32(h1));
  }
  *(ushort8*)(dhi + i) = hi;
  *(ushort8*)(dlo + i) = lo;
}

// ---------------------------------------------------------------------------
// Kernel 2: W [H,C,D] fp32 -> Wt_hi/lo [H,D,C] bf16 (transposed per head).
// ---------------------------------------------------------------------------
__global__ __launch_bounds__(256) void cast_split_Wt(
    const float* __restrict__ W, unsigned short* __restrict__ whi,
    unsigned short* __restrict__ wlo) {
  int o = blockIdx.x * 256 + threadIdx.x;      // [0, 4*128*512)
  int hd = o >> 16;                             // head
  int rem = o & 65535;
  int d = rem >> 9;                             // [0,128)
  int c = rem & 511;                            // [0,512)
  float v = W[((size_t)(hd * 512 + c)) * 128 + d];
  unsigned short h0 = f32_to_bf16(v);
  whi[o] = h0;
  wlo[o] = f32_to_bf16(v - bf16_to_f32(h0));
}

// ---------------------------------------------------------------------------
// Kernel 3: projection GEMM  hp = h @ Wall + bias   ([32768x512]@[512x512])
// split-bf16 3-term.  128x128 tile, BK=32, 4 waves (2x2), 16x16x32 MFMA.
// Epilogue: stage through LDS (reuse Ah/Al), write hp [b*512+s][c] coalesced.
// ---------------------------------------------------------------------------
__global__ __launch_bounds__(256, 2) void proj_gemm(
    const unsigned short* __restrict__ ahi, const unsigned short* __restrict__ alo,
    const unsigned short* __restrict__ whi, const unsigned short* __restrict__ wlo,
    const float* __restrict__ bias, unsigned short* __restrict__ hp_hi,
    unsigned short* __restrict__ hp_lo) {
  int bid = blockIdx.x;
  int swz = (bid & 7) * 128 + (bid >> 3);       // XCD-contiguous work chunks
  int nt = swz & 3, mt = swz >> 2;
  int m0 = mt * 128, n0 = nt * 128;             // n-tile == head nt

  __shared__ alignas(16) unsigned short Ah[128 * 32], Al[128 * 32];
  __shared__ alignas(16) unsigned short Bh[128 * 32], Bl[128 * 32];

  int tid = threadIdx.x, wv = tid >> 6, lane = tid & 63;
  int l15 = lane & 15, l4 = lane >> 4;
  int wr = wv >> 1, wc = wv & 1;

  f32x4 acc[4][4];
#pragma unroll
  for (int a = 0; a < 4; ++a)
#pragma unroll
    for (int b = 0; b < 4; ++b) acc[a][b] = (f32x4){0.f, 0.f, 0.f, 0.f};

  for (int ks = 0; ks < 16; ++ks) {
    int k0 = ks * 32;
    for (int i = wv; i < 32; i += 4) {
      int grp = i >> 3, j = i & 7;
      int row = j * 16 + (lane >> 2);
      int off = (lane & 3) * 16;
      int sw = ((row >> 1) & 3) << 4;
      const unsigned short* sb;
      unsigned short* db;
      size_t srcoff;
      if (grp == 0)      { sb = ahi; db = Ah; srcoff = ((size_t)(m0 + row) * 512 + k0) * 2; }
      else if (grp == 1) { sb = alo; db = Al; srcoff = ((size_t)(m0 + row) * 512 + k0) * 2; }
      else if (grp == 2) { sb = whi; db = Bh; srcoff = ((size_t)(nt * 128 + row) * 512 + k0) * 2; }
      else               { sb = wlo; db = Bl; srcoff = ((size_t)(nt * 128 + row) * 512 + k0) * 2; }
      GLD16((const char*)sb + srcoff + (off ^ sw), db + j * 512);
    }
    __syncthreads();

    bf16x8 fah[4], fal[4], fbh[4], fbl[4];
#pragma unroll
    for (int f = 0; f < 4; ++f) {
      int mr = wr * 64 + f * 16 + l15;
      int aadr = mr * 64 + ((16 * l4) ^ (((mr >> 1) & 3) << 4));
      fah[f] = *(const bf16x8*)((const char*)Ah + aadr);
      fal[f] = *(const bf16x8*)((const char*)Al + aadr);
      int nr = wc * 64 + f * 16 + l15;
      int badr = nr * 64 + ((16 * l4) ^ (((nr >> 1) & 3) << 4));
      fbh[f] = *(const bf16x8*)((const char*)Bh + badr);
      fbl[f] = *(const bf16x8*)((const char*)Bl + badr);
    }
#pragma unroll
    for (int a = 0; a < 4; ++a)
#pragma unroll
      for (int b = 0; b < 4; ++b) {
        acc[a][b] = mfma16(fah[a], fbh[b], acc[a][b]);
        acc[a][b] = mfma16(fah[a], fbl[b], acc[a][b]);
        acc[a][b] = mfma16(fal[a], fbh[b], acc[a][b]);
      }
    __syncthreads();
  }

  // epilogue: +bias, RNE split, LDS-staged coalesced writes of hp rows.
#pragma unroll
  for (int a = 0; a < 4; ++a) {
    __syncthreads();
#pragma unroll
    for (int b = 0; b < 4; ++b) {
      int cloc = wc * 64 + b * 16 + l15;
      float bv = bias[n0 + cloc];
#pragma unroll
      for (int r = 0; r < 4; ++r) {
        int rloc = wr * 16 + 4 * l4 + r;
        float v = acc[a][b][r] + bv;
        unsigned short hh = f32_to_bf16(v);
        Ah[rloc * 128 + cloc] = hh;
        Al[rloc * 128 + cloc] = f32_to_bf16(v - bf16_to_f32(hh));
      }
    }
    __syncthreads();
    int rr = tid >> 3, c16 = (tid & 7) * 16;
    int mg = m0 + (rr >> 4) * 64 + a * 16 + (rr & 15);
    bf16x8 vh0 = *(const bf16x8*)(Ah + rr * 128 + c16);
    bf16x8 vh1 = *(const bf16x8*)(Ah + rr * 128 + c16 + 8);
    bf16x8 vl0 = *(const bf16x8*)(Al + rr * 128 + c16);
    bf16x8 vl1 = *(const bf16x8*)(Al + rr * 128 + c16 + 8);
    *(bf16x8*)(hp_hi + (size_t)mg * 512 + n0 + c16) = vh0;
    *(bf16x8*)(hp_hi + (size_t)mg * 512 + n0 + c16 + 8) = vh1;
    *(bf16x8*)(hp_lo + (size_t)mg * 512 + n0 + c16) = vl0;
    *(bf16x8*)(hp_lo + (size_t)mg * 512 + n0 + c16 + 8) = vl1;
  }
}

// ---------------------------------------------------------------------------
// Kernel 5: flash attention.  Block = (b, head, q-tile of 64), 4 waves x 16 q.
// K in subtiled [8 sd][32 kv][16 d] layout, double-buffered.  QK^T reads one
// b128 per fragment; PV B-frags via ds_read_b64_tr_b16 from K_hi with the
// CANONICAL per-lane address (base + lane*8B): lane gets d=16vf+l15,
// kv = 16h + 4*l4 + j  = the pi slots.  One barrier per tile.  2 blk/CU cap.
// ---------------------------------------------------------------------------
__global__ __launch_bounds__(256, 2) void attn_kernel(
    const unsigned short* __restrict__ hp_hi, const unsigned short* __restrict__ hp_lo,
    const float* __restrict__ adj, float* __restrict__ out) {
  int bid = blockIdx.x;
  int swz = (bid & 7) * 256 + (bid >> 3);       // 8 q-tiles of one (b,h) per XCD
  int qt = swz & 7;
  int hd = (swz >> 3) & 3;
  int bb = swz >> 5;
  int q0 = qt * 64;

  __shared__ alignas(16) unsigned short SM[28672];     // 56 KB (occupancy cap)
  // buf0: K_hi @0, K_lo @4096 ; buf1: K_hi @8192, K_lo @12288  (u16 offsets)
  // each K_x = [8 sd][32 kv][16 d] subtiled (1KB per subtile)

  int tid = threadIdx.x, w = tid >> 6, lane = tid & 63;
  int l15 = lane & 15, l4 = lane >> 4;
  int qg = q0 + w * 16 + l15;                   // this lane's softmax q row

  // Q fragments (B-operand: n=q at l&15, k=d contiguous), hi+lo, in registers
  bf16x8 qh[4], ql[4];
  {
    size_t base = ((size_t)bb * 512 + qg) * 512 + hd * 128 + 8 * l4;
#pragma unroll
    for (int ds = 0; ds < 4; ++ds) {
      qh[ds] = *(const bf16x8*)(hp_hi + base + ds * 32);
      ql[ds] = *(const bf16x8*)(hp_lo + base + ds * 32);
    }
  }

  f32x4 o[8];
#pragma unroll
  for (int vf = 0; vf < 8; ++vf) o[vf] = (f32x4){0.f, 0.f, 0.f, 0.f};
  float m_run = -3.0e38f, l_run = 0.f;

  // staging roles: w0 K_hi sd0-3, w1 K_hi sd4-7, w2 K_lo sd0-3, w3 K_lo sd4-7
  const unsigned short* ssb = (w & 2) ? hp_lo : hp_hi;
  int sdst = (w & 2) ? 4096 : 0;                // u16 offset within buffer
  int sdbase = (w & 1) * 4;
  int skv = lane >> 1, sdh = lane & 1;          // lane i -> (kv=i>>1, dhalf)

  // ---- prologue: stage K[0] into buf0 (subtiled)
  {
    size_t rowb = ((size_t)(bb * 512 + skv)) * 1024 + hd * 256 + sdh * 16;
#pragma unroll
    for (int s2 = 0; s2 < 4; ++s2) {
      int sd = sdbase + s2;
      GLD16((const char*)ssb + rowb + sd * 32, SM + sdst + sd * 512);
    }
  }
  __syncthreads();

  for (int t = 0; t < 16; ++t) {
    int kv0 = t * 32;
    const unsigned short* Kb = SM + ((t & 1) << 13);
    const unsigned short* Khi = Kb;
    const unsigned short* Klo = Kb + 4096;

    // ---- stage K[t+1] into the other buffer (drained at end-of-tile barrier)
    if (t < 15) {
      unsigned short* Nb = SM + (((t + 1) & 1) << 13) + sdst;
      size_t rowb = ((size_t)(bb * 512 + kv0 + 32 + skv)) * 1024 + hd * 256 + sdh * 16;
#pragma unroll
      for (int s2 = 0; s2 < 4; ++s2) {
        int sd = sdbase + s2;
        GLD16((const char*)ssb + rowb + sd * 32, Nb + sd * 512);
      }
    }
    // adj loads early (latency hidden under compute)
    f32x4 av0 = *(const f32x4*)(adj + (size_t)qg * 512 + kv0 + 4 * l4);
    f32x4 av1 = *(const f32x4*)(adj + (size_t)qg * 512 + kv0 + 16 + 4 * l4);

    // ---- scores = K @ Q^T (swapped): lane q=l15, kv = {4*l4+r, 16+4*l4+r}
    // fragment (row r, d = ds*32+8*l4..+7) at byte sd*1024 + r*32 + 16*(l4&1),
    // sd = 2*ds + (l4>>1)
    f32x4 sc0 = {0.f, 0.f, 0.f, 0.f}, sc1 = {0.f, 0.f, 0.f, 0.f};
#pragma unroll
    for (int ds = 0; ds < 4; ++ds) {
      int boff = (2 * ds + (l4 >> 1)) * 1024 + 16 * (l4 & 1);
      int a0 = boff + l15 * 32;
      int a1 = boff + (16 + l15) * 32;
      bf16x8 kh0 = *(const bf16x8*)((const char*)Khi + a0);
      bf16x8 kl0 = *(const bf16x8*)((const char*)Klo + a0);
      bf16x8 kh1 = *(const bf16x8*)((const char*)Khi + a1);
      bf16x8 kl1 = *(const bf16x8*)((const char*)Klo + a1);
      sc0 = mfma16(kh0, qh[ds], sc0); sc1 = mfma16(kh1, qh[ds], sc1);
      sc0 = mfma16(kh0, ql[ds], sc0); sc1 = mfma16(kh1, ql[ds], sc1);
      sc0 = mfma16(kl0, qh[ds], sc0); sc1 = mfma16(kl1, qh[ds], sc1);
    }

    // ---- adj multiply + online softmax (row q = l15; kv in-lane)
    float p0[4], p1[4];
    float tm = -3.0e38f;
#pragma unroll
    for (int r = 0; r < 4; ++r) {
      p0[r] = sc0[r] * av0[r];
      p1[r] = sc1[r] * av1[r];
      tm = fmaxf(tm, fmaxf(p0[r], p1[r]));
    }
    tm = fmaxf(tm, __shfl_xor(tm, 16));
    tm = fmaxf(tm, __shfl_xor(tm, 32));
    if (__any(tm > m_run + 8.0f)) {             // T13 defer-rescale
      float mn = fmaxf(m_run, tm);
      float scl = __expf(m_run - mn);
      m_run = mn;
      l_run *= scl;
      f32x4 s4;
#pragma unroll
      for (int r = 0; r < 4; ++r) s4[r] = bperm_f(4 * l4 + r, scl);
#pragma unroll
      for (int vf = 0; vf < 8; ++vf)
#pragma unroll
        for (int r = 0; r < 4; ++r) o[vf][r] *= s4[r];
    }
    float ps = 0.f;
#pragma unroll
    for (int r = 0; r < 4; ++r) {
      p0[r] = __expf(p0[r] - m_run); ps += p0[r];
      p1[r] = __expf(p1[r] - m_run); ps += p1[r];
    }
    ps += __shfl_xor(ps, 16);
    ps += __shfl_xor(ps, 32);
    l_run += ps;

    // ---- pack P (trunc hi + residual lo) into pi-ordered A-frags
    union PU { bf16x8 v; unsigned u[4]; } pah, pal;
#pragma unroll
    for (int i = 0; i < 4; ++i) {
      float fa = (i < 2) ? p0[2 * i] : p1[2 * (i - 2)];
      float fb = (i < 2) ? p0[2 * i + 1] : p1[2 * (i - 2) + 1];
      unsigned ua = __float_as_uint(fa), ub = __float_as_uint(fb);
      pah.u[i] = (ua >> 16) | (ub & 0xFFFF0000u);
      float la = fa - __uint_as_float(ua & 0xFFFF0000u);
      float lb = fb - __uint_as_float(ub & 0xFFFF0000u);
      pal.u[i] = (__float_as_uint(la) >> 16) | (__float_as_uint(lb) & 0xFFFF0000u);
    }

    // ---- O += P @ V_hi: B-frags via HW transpose read from K_hi (subtiled).
    // per-lane canonical addr: base(vf,h) + lane*8B ->
    //   lane l elem j = K[kv = 16h + 4*l4 + j][d = 16*vf + l15]
    const unsigned short* trb = Khi + lane * 4;
    union VU { bf16x8 v; uint2v u2[2]; } vh[8];
#pragma unroll
    for (int vf = 0; vf < 8; ++vf) {
      vh[vf].u2[0] = tr_read(trb + vf * 512);
      vh[vf].u2[1] = tr_read(trb + vf * 512 + 256);
    }
    asm volatile("s_waitcnt lgkmcnt(0)" ::: "memory");
    __builtin_amdgcn_sched_barrier(0);
#pragma unroll
    for (int vf = 0; vf < 8; ++vf) {
      o[vf] = mfma16(pah.v, vh[vf].v, o[vf]);
      o[vf] = mfma16(pal.v, vh[vf].v, o[vf]);
    }
    __syncthreads();   // K[t+1] arrived (producer vmcnt drained); WAR on buf
  }

  // ---- epilogue: divide by row sums, stage O in LDS, coalesced f32 writes
  float rinv = 1.0f / l_run;
  f32x4 r4;
#pragma unroll
  for (int r = 0; r < 4; ++r) r4[r] = bperm_f(4 * l4 + r, rinv);
  float* wbase = (float*)SM + w * 2048;         // [16][128] f32 per wave
#pragma unroll
  for (int vf = 0; vf < 8; ++vf)
#pragma unroll
    for (int r = 0; r < 4; ++r)
      wbase[(4 * l4 + r) * 128 + vf * 16 + l15] = o[vf][r] * r4[r];
  __syncthreads();
#pragma unroll
  for (int p = 0; p < 4; ++p) {
    int row = p * 4 + l4;
    f32x4 v0 = *(const f32x4*)(wbase + row * 128 + l15 * 8);
    f32x4 v1 = *(const f32x4*)(wbase + row * 128 + l15 * 8 + 4);
    size_t mg = (size_t)bb * 512 + q0 + w * 16 + row;
    float* op = out + mg * 512 + hd * 128 + l15 * 8;
    *(f32x4*)op = v0;
    *(f32x4*)(op + 4) = v1;
  }
}

// ---------------------------------------------------------------------------
// Kernel 6: LayerNorm (over C=512) + exact-erf GELU, in place on d_out.
// ---------------------------------------------------------------------------
__global__ __launch_bounds__(256) void ln_gelu_kernel(
    float* __restrict__ io, const float* __restrict__ gamma,
    const float* __restrict__ beta) {
  int w = threadIdx.x >> 6, lane = threadIdx.x & 63;
  size_t row = (size_t)blockIdx.x * 4 + w;
  float* p = io + row * 512;
  f32x4 x0 = *(const f32x4*)(p + lane * 8);
  f32x4 x1 = *(const f32x4*)(p + lane * 8 + 4);
  float s = x0[0] + x0[1] + x0[2] + x0[3] + x1[0] + x1[1] + x1[2] + x1[3];
#pragma unroll
  for (int off = 32; off >= 1; off >>= 1) s += __shfl_xor(s, off);
  float mu = s * (1.0f / 512.0f);
  float vs = 0.f;
#pragma unroll
  for (int e = 0; e < 4; ++e) {
    float d0 = x0[e] - mu; vs += d0 * d0;
    float d1 = x1[e] - mu; vs += d1 * d1;
  }
#pragma unroll
  for (int off = 32; off >= 1; off >>= 1) vs += __shfl_xor(vs, off);
  float rs = rsqrtf(vs * (1.0f / 512.0f) + 1e-5f);
  f32x4 g0 = *(const f32x4*)(gamma + lane * 8);
  f32x4 g1 = *(const f32x4*)(gamma + lane * 8 + 4);
  f32x4 b0 = *(const f32x4*)(beta + lane * 8);
  f32x4 b1 = *(const f32x4*)(beta + lane * 8 + 4);
  f32x4 y0, y1;
#pragma unroll
  for (int e = 0; e < 4; ++e) {
    float y = (x0[e] - mu) * rs * g0[e] + b0[e];
    y0[e] = 0.5f * y * (1.0f + erff(y * 0.70710678118654752f));
    float z = (x1[e] - mu) * rs * g1[e] + b1[e];
    y1[e] = 0.5f * z * (1.0f + erff(z * 0.70710678118654752f));
  }
  *(f32x4*)(p + lane * 8) = y0;
  *(f32x4*)(p + lane * 8 + 4) = y1;
}

// ---------------------------------------------------------------------------
// Host launcher.  Inputs: [0]=t [1]=h [2]=W [3]=b [4]=adj [5]=gamma [6]=beta
// Workspace (~135 MB):
//   h_hi   = ws + 0          (16.7M u16)
//   h_lo   = ws + 16777216
//   hp_hi  = ws + 33554432
//   hp_lo  = ws + 50331648
//   Wt_hi  = ws + 67108864   (262144 u16)
//   Wt_lo  = ws + 67371008
// ---------------------------------------------------------------------------
extern "C" void kernel_launch(void* const* d_in, const int* in_sizes, int n_in,
                              void* d_out, int out_size, void* d_ws, size_t ws_size,
                              hipStream_t stream) {
  const float* h     = (const float*)d_in[1];
  const float* W     = (const float*)d_in[2];
  const float* bias  = (const float*)d_in[3];
  const float* adj   = (const float*)d_in[4];
  const float* gamma = (const float*)d_in[5];
  const float* beta  = (const float*)d_in[6];
  float* out = (float*)d_out;

  unsigned short* ws = (unsigned short*)d_ws;
  unsigned short* h_hi   = ws;
  unsigned short* h_lo   = ws + 16777216;
  unsigned short* hp_hi  = ws + 33554432;
  unsigned short* hp_lo  = ws + 50331648;
  unsigned short* Wt_hi  = ws + 67108864;
  unsigned short* Wt_lo  = ws + 67371008;

  cast_split_h<<<8192, 256, 0, stream>>>(h, h_hi, h_lo);
  cast_split_Wt<<<1024, 256, 0, stream>>>(W, Wt_hi, Wt_lo);
  proj_gemm<<<1024, 256, 0, stream>>>(h_hi, h_lo, Wt_hi, Wt_lo, bias, hp_hi, hp_lo);
  attn_kernel<<<2048, 256, 0, stream>>>(hp_hi, hp_lo, adj, out);
  ln_gelu_kernel<<<8192, 256, 0, stream>>>(out, gamma, beta);
}

// Round 11
// 218.204 us; speedup vs baseline: 2.2068x; 1.0326x over previous
//
#include <hip/hip_runtime.h>
#include <stdint.h>

// ---------------------------------------------------------------------------
// GraphAttentionLayer fused pipeline, MI355X (gfx950)
// B=64 S=512 C=512 H=4 D=128.  Split-bf16 (hi+lo) 3-term MFMA for GEMM/QK^T.
// Round 11: bisect of the round-10 post-timing race.  Occupancy reverted to
// the round-9-proven 2 blocks/CU (56KB pad, launch_bounds(256,2)); PV stays
// single-term (trunc-bf16 P @ V_hi).  Hardening: explicit vmcnt(0) before
// in-loop barriers; "memory" clobber on tr_read asm.
// ---------------------------------------------------------------------------

typedef float  f32x4   __attribute__((ext_vector_type(4)));
typedef short  bf16x8  __attribute__((ext_vector_type(8)));
typedef unsigned short ushort8 __attribute__((ext_vector_type(8)));
typedef unsigned int   uint2v  __attribute__((ext_vector_type(2)));

#define GLD16(src, dst)                                                        \
  __builtin_amdgcn_global_load_lds(                                            \
      (const __attribute__((address_space(1))) void*)(src),                    \
      (__attribute__((address_space(3))) void*)(dst), 16, 0, 0)

__device__ __forceinline__ unsigned short f32_to_bf16(float x) {
  union { float f; unsigned int u; } v; v.f = x;
  unsigned int r = v.u + 0x7FFFu + ((v.u >> 16) & 1u);
  return (unsigned short)(r >> 16);
}
__device__ __forceinline__ float bf16_to_f32(unsigned short h) {
  union { float f; unsigned int u; } v; v.u = ((unsigned int)h) << 16;
  return v.f;
}
__device__ __forceinline__ f32x4 mfma16(bf16x8 a, bf16x8 b, f32x4 c) {
  return __builtin_amdgcn_mfma_f32_16x16x32_bf16(a, b, c, 0, 0, 0);
}
__device__ __forceinline__ float bperm_f(int srcLane, float v) {
  return __int_as_float(__builtin_amdgcn_ds_bpermute(srcLane << 2, __float_as_int(v)));
}
// HW transpose read.  Address must be the canonical per-lane b64 address
// (base + lane*8B).  Lane l elem j <- lds_bf16[base + (l&15) + j*16 + (l>>4)*64].
// "memory" clobber: pin ordering vs surrounding LDS ops.
__device__ __forceinline__ uint2v tr_read(const unsigned short* p) {
  uint2v r;
  asm volatile("ds_read_b64_tr_b16 %0, %1"
               : "=v"(r)
               : "v"((const __attribute__((address_space(3))) void*)p)
               : "memory");
  return r;
}

// ---------------------------------------------------------------------------
// Kernel 1: split h (fp32) -> h_hi, h_lo (bf16).  8 elems/thread.
// ---------------------------------------------------------------------------
__global__ __launch_bounds__(256) void cast_split_h(
    const float* __restrict__ src, unsigned short* __restrict__ dhi,
    unsigned short* __restrict__ dlo) {
  size_t i = ((size_t)blockIdx.x * 256 + threadIdx.x) * 8;
  f32x4 a = *(const f32x4*)(src + i);
  f32x4 b = *(const f32x4*)(src + i + 4);
  ushort8 hi, lo;
#pragma unroll
  for (int e = 0; e < 4; ++e) {
    unsigned short h0 = f32_to_bf16(a[e]);
    hi[e] = h0; lo[e] = f32_to_bf16(a[e] - bf16_to_f32(h0));
    unsigned short h1 = f32_to_bf16(b[e]);
    hi[4 + e] = h1; lo[4 + e] = f32_to_bf16(b[e] - bf16_to_f32(h1));
  }
  *(ushort8*)(dhi + i) = hi;
  *(ushort8*)(dlo + i) = lo;
}

// ---------------------------------------------------------------------------
// Kernel 2: W [H,C,D] fp32 -> Wt_hi/lo [H,D,C] bf16 (transposed per head).
// ---------------------------------------------------------------------------
__global__ __launch_bounds__(256) void cast_split_Wt(
    const float* __restrict__ W, unsigned short* __restrict__ whi,
    unsigned short* __restrict__ wlo) {
  int o = blockIdx.x * 256 + threadIdx.x;      // [0, 4*128*512)
  int hd = o >> 16;                             // head
  int rem = o & 65535;
  int d = rem >> 9;                             // [0,128)
  int c = rem & 511;                            // [0,512)
  float v = W[((size_t)(hd * 512 + c)) * 128 + d];
  unsigned short h0 = f32_to_bf16(v);
  whi[o] = h0;
  wlo[o] = f32_to_bf16(v - bf16_to_f32(h0));
}

// ---------------------------------------------------------------------------
// Kernel 3: projection GEMM  hp = h @ Wall + bias   ([32768x512]@[512x512])
// split-bf16 3-term.  128x128 tile, BK=32, 4 waves (2x2), 16x16x32 MFMA.
// Epilogue: stage through LDS (reuse Ah/Al), write hp [b*512+s][c] coalesced.
// ---------------------------------------------------------------------------
__global__ __launch_bounds__(256, 2) void proj_gemm(
    const unsigned short* __restrict__ ahi, const unsigned short* __restrict__ alo,
    const unsigned short* __restrict__ whi, const unsigned short* __restrict__ wlo,
    const float* __restrict__ bias, unsigned short* __restrict__ hp_hi,
    unsigned short* __restrict__ hp_lo) {
  int bid = blockIdx.x;
  int swz = (bid & 7) * 128 + (bid >> 3);       // XCD-contiguous work chunks
  int nt = swz & 3, mt = swz >> 2;
  int m0 = mt * 128, n0 = nt * 128;             // n-tile == head nt

  __shared__ alignas(16) unsigned short Ah[128 * 32], Al[128 * 32];
  __shared__ alignas(16) unsigned short Bh[128 * 32], Bl[128 * 32];

  int tid = threadIdx.x, wv = tid >> 6, lane = tid & 63;
  int l15 = lane & 15, l4 = lane >> 4;
  int wr = wv >> 1, wc = wv & 1;

  f32x4 acc[4][4];
#pragma unroll
  for (int a = 0; a < 4; ++a)
#pragma unroll
    for (int b = 0; b < 4; ++b) acc[a][b] = (f32x4){0.f, 0.f, 0.f, 0.f};

  for (int ks = 0; ks < 16; ++ks) {
    int k0 = ks * 32;
    for (int i = wv; i < 32; i += 4) {
      int grp = i >> 3, j = i & 7;
      int row = j * 16 + (lane >> 2);
      int off = (lane & 3) * 16;
      int sw = ((row >> 1) & 3) << 4;
      const unsigned short* sb;
      unsigned short* db;
      size_t srcoff;
      if (grp == 0)      { sb = ahi; db = Ah; srcoff = ((size_t)(m0 + row) * 512 + k0) * 2; }
      else if (grp == 1) { sb = alo; db = Al; srcoff = ((size_t)(m0 + row) * 512 + k0) * 2; }
      else if (grp == 2) { sb = whi; db = Bh; srcoff = ((size_t)(nt * 128 + row) * 512 + k0) * 2; }
      else               { sb = wlo; db = Bl; srcoff = ((size_t)(nt * 128 + row) * 512 + k0) * 2; }
      GLD16((const char*)sb + srcoff + (off ^ sw), db + j * 512);
    }
    __syncthreads();

    bf16x8 fah[4], fal[4], fbh[4], fbl[4];
#pragma unroll
    for (int f = 0; f < 4; ++f) {
      int mr = wr * 64 + f * 16 + l15;
      int aadr = mr * 64 + ((16 * l4) ^ (((mr >> 1) & 3) << 4));
      fah[f] = *(const bf16x8*)((const char*)Ah + aadr);
      fal[f] = *(const bf16x8*)((const char*)Al + aadr);
      int nr = wc * 64 + f * 16 + l15;
      int badr = nr * 64 + ((16 * l4) ^ (((nr >> 1) & 3) << 4));
      fbh[f] = *(const bf16x8*)((const char*)Bh + badr);
      fbl[f] = *(const bf16x8*)((const char*)Bl + badr);
    }
#pragma unroll
    for (int a = 0; a < 4; ++a)
#pragma unroll
      for (int b = 0; b < 4; ++b) {
        acc[a][b] = mfma16(fah[a], fbh[b], acc[a][b]);
        acc[a][b] = mfma16(fah[a], fbl[b], acc[a][b]);
        acc[a][b] = mfma16(fal[a], fbh[b], acc[a][b]);
      }
    __syncthreads();
  }

  // epilogue: +bias, RNE split, LDS-staged coalesced writes of hp rows.
#pragma unroll
  for (int a = 0; a < 4; ++a) {
    __syncthreads();
#pragma unroll
    for (int b = 0; b < 4; ++b) {
      int cloc = wc * 64 + b * 16 + l15;
      float bv = bias[n0 + cloc];
#pragma unroll
      for (int r = 0; r < 4; ++r) {
        int rloc = wr * 16 + 4 * l4 + r;
        float v = acc[a][b][r] + bv;
        unsigned short hh = f32_to_bf16(v);
        Ah[rloc * 128 + cloc] = hh;
        Al[rloc * 128 + cloc] = f32_to_bf16(v - bf16_to_f32(hh));
      }
    }
    __syncthreads();
    int rr = tid >> 3, c16 = (tid & 7) * 16;
    int mg = m0 + (rr >> 4) * 64 + a * 16 + (rr & 15);
    bf16x8 vh0 = *(const bf16x8*)(Ah + rr * 128 + c16);
    bf16x8 vh1 = *(const bf16x8*)(Ah + rr * 128 + c16 + 8);
    bf16x8 vl0 = *(const bf16x8*)(Al + rr * 128 + c16);
    bf16x8 vl1 = *(const bf16x8*)(Al + rr * 128 + c16 + 8);
    *(bf16x8*)(hp_hi + (size_t)mg * 512 + n0 + c16) = vh0;
    *(bf16x8*)(hp_hi + (size_t)mg * 512 + n0 + c16 + 8) = vh1;
    *(bf16x8*)(hp_lo + (size_t)mg * 512 + n0 + c16) = vl0;
    *(bf16x8*)(hp_lo + (size_t)mg * 512 + n0 + c16 + 8) = vl1;
  }
}

// ---------------------------------------------------------------------------
// Kernel 5: flash attention.  Block = (b, head, q-tile of 64), 4 waves x 16 q.
// K in subtiled [8 sd][32 kv][16 d] layout, double-buffered.  QK^T reads one
// b128 per fragment; PV B-frags via ds_read_b64_tr_b16 from K_hi (canonical
// per-lane address).  PV single-term: trunc-bf16(P) @ V_hi (denominator stays
// exact f32).  One barrier per tile with explicit vmcnt(0) drain.
// 56KB LDS pad -> 2 blocks/CU (round-9-proven regime).
// ---------------------------------------------------------------------------
__global__ __launch_bounds__(256, 2) void attn_kernel(
    const unsigned short* __restrict__ hp_hi, const unsigned short* __restrict__ hp_lo,
    const float* __restrict__ adj, float* __restrict__ out) {
  int bid = blockIdx.x;
  int swz = (bid & 7) * 256 + (bid >> 3);       // 8 q-tiles of one (b,h) per XCD
  int qt = swz & 7;
  int hd = (swz >> 3) & 3;
  int bb = swz >> 5;
  int q0 = qt * 64;

  __shared__ alignas(16) unsigned short SM[28672];     // 56 KB (2 blocks/CU)
  // buf0: K_hi @0, K_lo @4096 ; buf1: K_hi @8192, K_lo @12288  (u16 offsets)
  // each K_x = [8 sd][32 kv][16 d] subtiled (1KB per subtile)

  int tid = threadIdx.x, w = tid >> 6, lane = tid & 63;
  int l15 = lane & 15, l4 = lane >> 4;
  int qg = q0 + w * 16 + l15;                   // this lane's softmax q row

  // Q fragments (B-operand: n=q at l&15, k=d contiguous), hi+lo, in registers
  bf16x8 qh[4], ql[4];
  {
    size_t base = ((size_t)bb * 512 + qg) * 512 + hd * 128 + 8 * l4;
#pragma unroll
    for (int ds = 0; ds < 4; ++ds) {
      qh[ds] = *(const bf16x8*)(hp_hi + base + ds * 32);
      ql[ds] = *(const bf16x8*)(hp_lo + base + ds * 32);
    }
  }

  f32x4 o[8];
#pragma unroll
  for (int vf = 0; vf < 8; ++vf) o[vf] = (f32x4){0.f, 0.f, 0.f, 0.f};
  float m_run = -3.0e38f, l_run = 0.f;

  // staging roles: w0 K_hi sd0-3, w1 K_hi sd4-7, w2 K_lo sd0-3, w3 K_lo sd4-7
  const unsigned short* ssb = (w & 2) ? hp_lo : hp_hi;
  int sdst = (w & 2) ? 4096 : 0;                // u16 offset within buffer
  int sdbase = (w & 1) * 4;
  int skv = lane >> 1, sdh = lane & 1;          // lane i -> (kv=i>>1, dhalf)

  // ---- prologue: stage K[0] into buf0 (subtiled)
  {
    size_t rowb = ((size_t)(bb * 512 + skv)) * 1024 + hd * 256 + sdh * 16;
#pragma unroll
    for (int s2 = 0; s2 < 4; ++s2) {
      int sd = sdbase + s2;
      GLD16((const char*)ssb + rowb + sd * 32, SM + sdst + sd * 512);
    }
  }
  asm volatile("s_waitcnt vmcnt(0)" ::: "memory");
  __syncthreads();

  for (int t = 0; t < 16; ++t) {
    int kv0 = t * 32;
    const unsigned short* Kb = SM + ((t & 1) << 13);
    const unsigned short* Khi = Kb;
    const unsigned short* Klo = Kb + 4096;

    // ---- stage K[t+1] into the other buffer (drained at end-of-tile barrier)
    if (t < 15) {
      unsigned short* Nb = SM + (((t + 1) & 1) << 13) + sdst;
      size_t rowb = ((size_t)(bb * 512 + kv0 + 32 + skv)) * 1024 + hd * 256 + sdh * 16;
#pragma unroll
      for (int s2 = 0; s2 < 4; ++s2) {
        int sd = sdbase + s2;
        GLD16((const char*)ssb + rowb + sd * 32, Nb + sd * 512);
      }
    }
    // adj loads early (latency hidden under compute)
    f32x4 av0 = *(const f32x4*)(adj + (size_t)qg * 512 + kv0 + 4 * l4);
    f32x4 av1 = *(const f32x4*)(adj + (size_t)qg * 512 + kv0 + 16 + 4 * l4);

    // ---- scores = K @ Q^T (swapped): lane q=l15, kv = {4*l4+r, 16+4*l4+r}
    // fragment (row r, d = ds*32+8*l4..+7) at byte sd*1024 + r*32 + 16*(l4&1),
    // sd = 2*ds + (l4>>1)
    f32x4 sc0 = {0.f, 0.f, 0.f, 0.f}, sc1 = {0.f, 0.f, 0.f, 0.f};
#pragma unroll
    for (int ds = 0; ds < 4; ++ds) {
      int boff = (2 * ds + (l4 >> 1)) * 1024 + 16 * (l4 & 1);
      int a0 = boff + l15 * 32;
      int a1 = boff + (16 + l15) * 32;
      bf16x8 kh0 = *(const bf16x8*)((const char*)Khi + a0);
      bf16x8 kl0 = *(const bf16x8*)((const char*)Klo + a0);
      bf16x8 kh1 = *(const bf16x8*)((const char*)Khi + a1);
      bf16x8 kl1 = *(const bf16x8*)((const char*)Klo + a1);
      sc0 = mfma16(kh0, qh[ds], sc0); sc1 = mfma16(kh1, qh[ds], sc1);
      sc0 = mfma16(kh0, ql[ds], sc0); sc1 = mfma16(kh1, ql[ds], sc1);
      sc0 = mfma16(kl0, qh[ds], sc0); sc1 = mfma16(kl1, qh[ds], sc1);
    }

    // ---- adj multiply + online softmax (row q = l15; kv in-lane)
    float p0[4], p1[4];
    float tm = -3.0e38f;
#pragma unroll
    for (int r = 0; r < 4; ++r) {
      p0[r] = sc0[r] * av0[r];
      p1[r] = sc1[r] * av1[r];
      tm = fmaxf(tm, fmaxf(p0[r], p1[r]));
    }
    tm = fmaxf(tm, __shfl_xor(tm, 16));
    tm = fmaxf(tm, __shfl_xor(tm, 32));
    if (__any(tm > m_run + 8.0f)) {             // T13 defer-rescale
      float mn = fmaxf(m_run, tm);
      float scl = __expf(m_run - mn);
      m_run = mn;
      l_run *= scl;
      f32x4 s4;
#pragma unroll
      for (int r = 0; r < 4; ++r) s4[r] = bperm_f(4 * l4 + r, scl);
#pragma unroll
      for (int vf = 0; vf < 8; ++vf)
#pragma unroll
        for (int r = 0; r < 4; ++r) o[vf][r] *= s4[r];
    }
    float ps = 0.f;
#pragma unroll
    for (int r = 0; r < 4; ++r) {
      p0[r] = __expf(p0[r] - m_run); ps += p0[r];
      p1[r] = __expf(p1[r] - m_run); ps += p1[r];
    }
    ps += __shfl_xor(ps, 16);
    ps += __shfl_xor(ps, 32);
    l_run += ps;

    // ---- pack P (trunc-bf16 only; denominator stays exact f32) pi-ordered
    union PU { bf16x8 v; unsigned u[4]; } pah;
#pragma unroll
    for (int i = 0; i < 4; ++i) {
      float fa = (i < 2) ? p0[2 * i] : p1[2 * (i - 2)];
      float fb = (i < 2) ? p0[2 * i + 1] : p1[2 * (i - 2) + 1];
      pah.u[i] = (__float_as_uint(fa) >> 16) |
                 (__float_as_uint(fb) & 0xFFFF0000u);
    }

    // ---- O += P @ V_hi: B-frags via HW transpose read from K_hi (subtiled).
    // per-lane canonical addr: base(vf,h) + lane*8B ->
    //   lane l elem j = K[kv = 16h + 4*l4 + j][d = 16*vf + l15]
    const unsigned short* trb = Khi + lane * 4;
    union VU { bf16x8 v; uint2v u2[2]; } vh[8];
#pragma unroll
    for (int vf = 0; vf < 8; ++vf) {
      vh[vf].u2[0] = tr_read(trb + vf * 512);
      vh[vf].u2[1] = tr_read(trb + vf * 512 + 256);
    }
    asm volatile("s_waitcnt lgkmcnt(0)" ::: "memory");
    __builtin_amdgcn_sched_barrier(0);
#pragma unroll
    for (int vf = 0; vf < 8; ++vf)
      o[vf] = mfma16(pah.v, vh[vf].v, o[vf]);
    // explicit drain of this wave's GLD16s (K[t+1]) + LDS ops before barrier
    asm volatile("s_waitcnt vmcnt(0) lgkmcnt(0)" ::: "memory");
    __syncthreads();   // K[t+1] visible to all; WAR turnover on buf[t&1]
  }

  // ---- epilogue: divide by row sums, stage O in LDS, coalesced f32 writes
  float rinv = 1.0f / l_run;
  f32x4 r4;
#pragma unroll
  for (int r = 0; r < 4; ++r) r4[r] = bperm_f(4 * l4 + r, rinv);
  float* wbase = (float*)SM + w * 2048;         // [16][128] f32 per wave
#pragma unroll
  for (int vf = 0; vf < 8; ++vf)
#pragma unroll
    for (int r = 0; r < 4; ++r)
      wbase[(4 * l4 + r) * 128 + vf * 16 + l15] = o[vf][r] * r4[r];
  __syncthreads();
#pragma unroll
  for (int p = 0; p < 4; ++p) {
    int row = p * 4 + l4;
    f32x4 v0 = *(const f32x4*)(wbase + row * 128 + l15 * 8);
    f32x4 v1 = *(const f32x4*)(wbase + row * 128 + l15 * 8 + 4);
    size_t mg = (size_t)bb * 512 + q0 + w * 16 + row;
    float* op = out + mg * 512 + hd * 128 + l15 * 8;
    *(f32x4*)op = v0;
    *(f32x4*)(op + 4) = v1;
  }
}

// ---------------------------------------------------------------------------
// Kernel 6: LayerNorm (over C=512) + exact-erf GELU, in place on d_out.
// ---------------------------------------------------------------------------
__global__ __launch_bounds__(256) void ln_gelu_kernel(
    float* __restrict__ io, const float* __restrict__ gamma,
    const float* __restrict__ beta) {
  int w = threadIdx.x >> 6, lane = threadIdx.x & 63;
  size_t row = (size_t)blockIdx.x * 4 + w;
  float* p = io + row * 512;
  f32x4 x0 = *(const f32x4*)(p + lane * 8);
  f32x4 x1 = *(const f32x4*)(p + lane * 8 + 4);
  float s = x0[0] + x0[1] + x0[2] + x0[3] + x1[0] + x1[1] + x1[2] + x1[3];
#pragma unroll
  for (int off = 32; off >= 1; off >>= 1) s += __shfl_xor(s, off);
  float mu = s * (1.0f / 512.0f);
  float vs = 0.f;
#pragma unroll
  for (int e = 0; e < 4; ++e) {
    float d0 = x0[e] - mu; vs += d0 * d0;
    float d1 = x1[e] - mu; vs += d1 * d1;
  }
#pragma unroll
  for (int off = 32; off >= 1; off >>= 1) vs += __shfl_xor(vs, off);
  float rs = rsqrtf(vs * (1.0f / 512.0f) + 1e-5f);
  f32x4 g0 = *(const f32x4*)(gamma + lane * 8);
  f32x4 g1 = *(const f32x4*)(gamma + lane * 8 + 4);
  f32x4 b0 = *(const f32x4*)(beta + lane * 8);
  f32x4 b1 = *(const f32x4*)(beta + lane * 8 + 4);
  f32x4 y0, y1;
#pragma unroll
  for (int e = 0; e < 4; ++e) {
    float y = (x0[e] - mu) * rs * g0[e] + b0[e];
    y0[e] = 0.5f * y * (1.0f + erff(y * 0.70710678118654752f));
    float z = (x1[e] - mu) * rs * g1[e] + b1[e];
    y1[e] = 0.5f * z * (1.0f + erff(z * 0.70710678118654752f));
  }
  *(f32x4*)(p + lane * 8) = y0;
  *(f32x4*)(p + lane * 8 + 4) = y1;
}

// ---------------------------------------------------------------------------
// Host launcher.  Inputs: [0]=t [1]=h [2]=W [3]=b [4]=adj [5]=gamma [6]=beta
// Workspace (~135 MB):
//   h_hi   = ws + 0          (16.7M u16)
//   h_lo   = ws + 16777216
//   hp_hi  = ws + 33554432
//   hp_lo  = ws + 50331648
//   Wt_hi  = ws + 67108864   (262144 u16)
//   Wt_lo  = ws + 67371008
// ---------------------------------------------------------------------------
extern "C" void kernel_launch(void* const* d_in, const int* in_sizes, int n_in,
                              void* d_out, int out_size, void* d_ws, size_t ws_size,
                              hipStream_t stream) {
  const float* h     = (const float*)d_in[1];
  const float* W     = (const float*)d_in[2];
  const float* bias  = (const float*)d_in[3];
  const float* adj   = (const float*)d_in[4];
  const float* gamma = (const float*)d_in[5];
  const float* beta  = (const float*)d_in[6];
  float* out = (float*)d_out;

  unsigned short* ws = (unsigned short*)d_ws;
  unsigned short* h_hi   = ws;
  unsigned short* h_lo   = ws + 16777216;
  unsigned short* hp_hi  = ws + 33554432;
  unsigned short* hp_lo  = ws + 50331648;
  unsigned short* Wt_hi  = ws + 67108864;
  unsigned short* Wt_lo  = ws + 67371008;

  cast_split_h<<<8192, 256, 0, stream>>>(h, h_hi, h_lo);
  cast_split_Wt<<<1024, 256, 0, stream>>>(W, Wt_hi, Wt_lo);
  proj_gemm<<<1024, 256, 0, stream>>>(h_hi, h_lo, Wt_hi, Wt_lo, bias, hp_hi, hp_lo);
  attn_kernel<<<2048, 256, 0, stream>>>(hp_hi, hp_lo, adj, out);
  ln_gelu_kernel<<<8192, 256, 0, stream>>>(out, gamma, beta);
}

// Round 12
// 211.735 us; speedup vs baseline: 2.2742x; 1.0306x over previous
//
#include <hip/hip_runtime.h>
#include <stdint.h>

// ---------------------------------------------------------------------------
// GraphAttentionLayer fused pipeline, MI355X (gfx950)
// B=64 S=512 C=512 H=4 D=128.  Split-bf16 (hi+lo) 3-term MFMA for GEMM/QK^T.
// Round 12: attn occupancy 2->3 blocks/CU retry WITH round-11 hardening
// (explicit vmcnt/lgkmcnt drains + tr_read memory clobber).  adj precast to
// bf16 (halves adj L2 footprint; exact for 0/1 masks), stored in dead h_hi.
// ---------------------------------------------------------------------------

typedef float  f32x4   __attribute__((ext_vector_type(4)));
typedef short  bf16x8  __attribute__((ext_vector_type(8)));
typedef unsigned short ushort8 __attribute__((ext_vector_type(8)));
typedef unsigned int   uint2v  __attribute__((ext_vector_type(2)));

#define GLD16(src, dst)                                                        \
  __builtin_amdgcn_global_load_lds(                                            \
      (const __attribute__((address_space(1))) void*)(src),                    \
      (__attribute__((address_space(3))) void*)(dst), 16, 0, 0)

__device__ __forceinline__ unsigned short f32_to_bf16(float x) {
  union { float f; unsigned int u; } v; v.f = x;
  unsigned int r = v.u + 0x7FFFu + ((v.u >> 16) & 1u);
  return (unsigned short)(r >> 16);
}
__device__ __forceinline__ float bf16_to_f32(unsigned int h) {
  union { float f; unsigned int u; } v; v.u = h << 16;
  return v.f;
}
__device__ __forceinline__ f32x4 mfma16(bf16x8 a, bf16x8 b, f32x4 c) {
  return __builtin_amdgcn_mfma_f32_16x16x32_bf16(a, b, c, 0, 0, 0);
}
__device__ __forceinline__ float bperm_f(int srcLane, float v) {
  return __int_as_float(__builtin_amdgcn_ds_bpermute(srcLane << 2, __float_as_int(v)));
}
// HW transpose read.  Address must be the canonical per-lane b64 address
// (base + lane*8B).  Lane l elem j <- lds_bf16[base + (l&15) + j*16 + (l>>4)*64].
__device__ __forceinline__ uint2v tr_read(const unsigned short* p) {
  uint2v r;
  asm volatile("ds_read_b64_tr_b16 %0, %1"
               : "=v"(r)
               : "v"((const __attribute__((address_space(3))) void*)p)
               : "memory");
  return r;
}

// ---------------------------------------------------------------------------
// Kernel 1: split h (fp32) -> h_hi, h_lo (bf16).  8 elems/thread.
// ---------------------------------------------------------------------------
__global__ __launch_bounds__(256) void cast_split_h(
    const float* __restrict__ src, unsigned short* __restrict__ dhi,
    unsigned short* __restrict__ dlo) {
  size_t i = ((size_t)blockIdx.x * 256 + threadIdx.x) * 8;
  f32x4 a = *(const f32x4*)(src + i);
  f32x4 b = *(const f32x4*)(src + i + 4);
  ushort8 hi, lo;
#pragma unroll
  for (int e = 0; e < 4; ++e) {
    unsigned short h0 = f32_to_bf16(a[e]);
    hi[e] = h0; lo[e] = f32_to_bf16(a[e] - bf16_to_f32(h0));
    unsigned short h1 = f32_to_bf16(b[e]);
    hi[4 + e] = h1; lo[4 + e] = f32_to_bf16(b[e] - bf16_to_f32(h1));
  }
  *(ushort8*)(dhi + i) = hi;
  *(ushort8*)(dlo + i) = lo;
}

// ---------------------------------------------------------------------------
// Kernel 2: W [H,C,D] fp32 -> Wt_hi/lo [H,D,C] bf16 (transposed per head).
// ---------------------------------------------------------------------------
__global__ __launch_bounds__(256) void cast_split_Wt(
    const float* __restrict__ W, unsigned short* __restrict__ whi,
    unsigned short* __restrict__ wlo) {
  int o = blockIdx.x * 256 + threadIdx.x;      // [0, 4*128*512)
  int hd = o >> 16;                             // head
  int rem = o & 65535;
  int d = rem >> 9;                             // [0,128)
  int c = rem & 511;                            // [0,512)
  float v = W[((size_t)(hd * 512 + c)) * 128 + d];
  unsigned short h0 = f32_to_bf16(v);
  whi[o] = h0;
  wlo[o] = f32_to_bf16(v - bf16_to_f32(h0));
}

// ---------------------------------------------------------------------------
// Kernel 2b: adj (fp32) -> bf16 (exact for 0/1 masks).  8 elems/thread.
// ---------------------------------------------------------------------------
__global__ __launch_bounds__(256) void cast_adj(
    const float* __restrict__ src, unsigned short* __restrict__ dst) {
  size_t i = ((size_t)blockIdx.x * 256 + threadIdx.x) * 8;
  f32x4 a = *(const f32x4*)(src + i);
  f32x4 b = *(const f32x4*)(src + i + 4);
  ushort8 o;
#pragma unroll
  for (int e = 0; e < 4; ++e) {
    o[e] = f32_to_bf16(a[e]);
    o[4 + e] = f32_to_bf16(b[e]);
  }
  *(ushort8*)(dst + i) = o;
}

// ---------------------------------------------------------------------------
// Kernel 3: projection GEMM  hp = h @ Wall + bias   ([32768x512]@[512x512])
// split-bf16 3-term.  128x128 tile, BK=32, 4 waves (2x2), 16x16x32 MFMA.
// Epilogue: stage through LDS (reuse Ah/Al), write hp [b*512+s][c] coalesced.
// ---------------------------------------------------------------------------
__global__ __launch_bounds__(256, 2) void proj_gemm(
    const unsigned short* __restrict__ ahi, const unsigned short* __restrict__ alo,
    const unsigned short* __restrict__ whi, const unsigned short* __restrict__ wlo,
    const float* __restrict__ bias, unsigned short* __restrict__ hp_hi,
    unsigned short* __restrict__ hp_lo) {
  int bid = blockIdx.x;
  int swz = (bid & 7) * 128 + (bid >> 3);       // XCD-contiguous work chunks
  int nt = swz & 3, mt = swz >> 2;
  int m0 = mt * 128, n0 = nt * 128;             // n-tile == head nt

  __shared__ alignas(16) unsigned short Ah[128 * 32], Al[128 * 32];
  __shared__ alignas(16) unsigned short Bh[128 * 32], Bl[128 * 32];

  int tid = threadIdx.x, wv = tid >> 6, lane = tid & 63;
  int l15 = lane & 15, l4 = lane >> 4;
  int wr = wv >> 1, wc = wv & 1;

  f32x4 acc[4][4];
#pragma unroll
  for (int a = 0; a < 4; ++a)
#pragma unroll
    for (int b = 0; b < 4; ++b) acc[a][b] = (f32x4){0.f, 0.f, 0.f, 0.f};

  for (int ks = 0; ks < 16; ++ks) {
    int k0 = ks * 32;
    for (int i = wv; i < 32; i += 4) {
      int grp = i >> 3, j = i & 7;
      int row = j * 16 + (lane >> 2);
      int off = (lane & 3) * 16;
      int sw = ((row >> 1) & 3) << 4;
      const unsigned short* sb;
      unsigned short* db;
      size_t srcoff;
      if (grp == 0)      { sb = ahi; db = Ah; srcoff = ((size_t)(m0 + row) * 512 + k0) * 2; }
      else if (grp == 1) { sb = alo; db = Al; srcoff = ((size_t)(m0 + row) * 512 + k0) * 2; }
      else if (grp == 2) { sb = whi; db = Bh; srcoff = ((size_t)(nt * 128 + row) * 512 + k0) * 2; }
      else               { sb = wlo; db = Bl; srcoff = ((size_t)(nt * 128 + row) * 512 + k0) * 2; }
      GLD16((const char*)sb + srcoff + (off ^ sw), db + j * 512);
    }
    __syncthreads();

    bf16x8 fah[4], fal[4], fbh[4], fbl[4];
#pragma unroll
    for (int f = 0; f < 4; ++f) {
      int mr = wr * 64 + f * 16 + l15;
      int aadr = mr * 64 + ((16 * l4) ^ (((mr >> 1) & 3) << 4));
      fah[f] = *(const bf16x8*)((const char*)Ah + aadr);
      fal[f] = *(const bf16x8*)((const char*)Al + aadr);
      int nr = wc * 64 + f * 16 + l15;
      int badr = nr * 64 + ((16 * l4) ^ (((nr >> 1) & 3) << 4));
      fbh[f] = *(const bf16x8*)((const char*)Bh + badr);
      fbl[f] = *(const bf16x8*)((const char*)Bl + badr);
    }
#pragma unroll
    for (int a = 0; a < 4; ++a)
#pragma unroll
      for (int b = 0; b < 4; ++b) {
        acc[a][b] = mfma16(fah[a], fbh[b], acc[a][b]);
        acc[a][b] = mfma16(fah[a], fbl[b], acc[a][b]);
        acc[a][b] = mfma16(fal[a], fbh[b], acc[a][b]);
      }
    __syncthreads();
  }

  // epilogue: +bias, RNE split, LDS-staged coalesced writes of hp rows.
#pragma unroll
  for (int a = 0; a < 4; ++a) {
    __syncthreads();
#pragma unroll
    for (int b = 0; b < 4; ++b) {
      int cloc = wc * 64 + b * 16 + l15;
      float bv = bias[n0 + cloc];
#pragma unroll
      for (int r = 0; r < 4; ++r) {
        int rloc = wr * 16 + 4 * l4 + r;
        float v = acc[a][b][r] + bv;
        unsigned short hh = f32_to_bf16(v);
        Ah[rloc * 128 + cloc] = hh;
        Al[rloc * 128 + cloc] = f32_to_bf16(v - bf16_to_f32(hh));
      }
    }
    __syncthreads();
    int rr = tid >> 3, c16 = (tid & 7) * 16;
    int mg = m0 + (rr >> 4) * 64 + a * 16 + (rr & 15);
    bf16x8 vh0 = *(const bf16x8*)(Ah + rr * 128 + c16);
    bf16x8 vh1 = *(const bf16x8*)(Ah + rr * 128 + c16 + 8);
    bf16x8 vl0 = *(const bf16x8*)(Al + rr * 128 + c16);
    bf16x8 vl1 = *(const bf16x8*)(Al + rr * 128 + c16 + 8);
    *(bf16x8*)(hp_hi + (size_t)mg * 512 + n0 + c16) = vh0;
    *(bf16x8*)(hp_hi + (size_t)mg * 512 + n0 + c16 + 8) = vh1;
    *(bf16x8*)(hp_lo + (size_t)mg * 512 + n0 + c16) = vl0;
    *(bf16x8*)(hp_lo + (size_t)mg * 512 + n0 + c16 + 8) = vl1;
  }
}

// ---------------------------------------------------------------------------
// Kernel 5: flash attention.  Block = (b, head, q-tile of 64), 4 waves x 16 q.
// K in subtiled [8 sd][32 kv][16 d] layout, double-buffered.  QK^T reads one
// b128 per fragment; PV B-frags via ds_read_b64_tr_b16 from K_hi (canonical
// per-lane address).  PV single-term: trunc-bf16(P) @ V_hi.  One barrier per
// tile with explicit vmcnt/lgkm drains.  48KB LDS pad -> 3 blocks/CU.
// adj read as bf16.
// ---------------------------------------------------------------------------
__global__ __launch_bounds__(256, 3) void attn_kernel(
    const unsigned short* __restrict__ hp_hi, const unsigned short* __restrict__ hp_lo,
    const unsigned short* __restrict__ adjb, float* __restrict__ out) {
  int bid = blockIdx.x;
  int swz = (bid & 7) * 256 + (bid >> 3);       // 8 q-tiles of one (b,h) per XCD
  int qt = swz & 7;
  int hd = (swz >> 3) & 3;
  int bb = swz >> 5;
  int q0 = qt * 64;

  __shared__ alignas(16) unsigned short SM[24576];     // 48 KB -> 3 blocks/CU
  // buf0: K_hi @0, K_lo @4096 ; buf1: K_hi @8192, K_lo @12288  (u16 offsets)
  // each K_x = [8 sd][32 kv][16 d] subtiled (1KB per subtile)

  int tid = threadIdx.x, w = tid >> 6, lane = tid & 63;
  int l15 = lane & 15, l4 = lane >> 4;
  int qg = q0 + w * 16 + l15;                   // this lane's softmax q row

  // Q fragments (B-operand: n=q at l&15, k=d contiguous), hi+lo, in registers
  bf16x8 qh[4], ql[4];
  {
    size_t base = ((size_t)bb * 512 + qg) * 512 + hd * 128 + 8 * l4;
#pragma unroll
    for (int ds = 0; ds < 4; ++ds) {
      qh[ds] = *(const bf16x8*)(hp_hi + base + ds * 32);
      ql[ds] = *(const bf16x8*)(hp_lo + base + ds * 32);
    }
  }

  f32x4 o[8];
#pragma unroll
  for (int vf = 0; vf < 8; ++vf) o[vf] = (f32x4){0.f, 0.f, 0.f, 0.f};
  float m_run = -3.0e38f, l_run = 0.f;

  // staging roles: w0 K_hi sd0-3, w1 K_hi sd4-7, w2 K_lo sd0-3, w3 K_lo sd4-7
  const unsigned short* ssb = (w & 2) ? hp_lo : hp_hi;
  int sdst = (w & 2) ? 4096 : 0;                // u16 offset within buffer
  int sdbase = (w & 1) * 4;
  int skv = lane >> 1, sdh = lane & 1;          // lane i -> (kv=i>>1, dhalf)

  // ---- prologue: stage K[0] into buf0 (subtiled)
  {
    size_t rowb = ((size_t)(bb * 512 + skv)) * 1024 + hd * 256 + sdh * 16;
#pragma unroll
    for (int s2 = 0; s2 < 4; ++s2) {
      int sd = sdbase + s2;
      GLD16((const char*)ssb + rowb + sd * 32, SM + sdst + sd * 512);
    }
  }
  asm volatile("s_waitcnt vmcnt(0)" ::: "memory");
  __syncthreads();

  for (int t = 0; t < 16; ++t) {
    int kv0 = t * 32;
    const unsigned short* Kb = SM + ((t & 1) << 13);
    const unsigned short* Khi = Kb;
    const unsigned short* Klo = Kb + 4096;

    // ---- stage K[t+1] into the other buffer (drained at end-of-tile barrier)
    if (t < 15) {
      unsigned short* Nb = SM + (((t + 1) & 1) << 13) + sdst;
      size_t rowb = ((size_t)(bb * 512 + kv0 + 32 + skv)) * 1024 + hd * 256 + sdh * 16;
#pragma unroll
      for (int s2 = 0; s2 < 4; ++s2) {
        int sd = sdbase + s2;
        GLD16((const char*)ssb + rowb + sd * 32, Nb + sd * 512);
      }
    }
    // adj loads early (bf16, latency hidden under compute)
    uint2 ua0 = *(const uint2*)(adjb + (size_t)qg * 512 + kv0 + 4 * l4);
    uint2 ua1 = *(const uint2*)(adjb + (size_t)qg * 512 + kv0 + 16 + 4 * l4);
    f32x4 av0, av1;
    av0[0] = bf16_to_f32(ua0.x & 0xFFFFu); av0[1] = bf16_to_f32(ua0.x >> 16);
    av0[2] = bf16_to_f32(ua0.y & 0xFFFFu); av0[3] = bf16_to_f32(ua0.y >> 16);
    av1[0] = bf16_to_f32(ua1.x & 0xFFFFu); av1[1] = bf16_to_f32(ua1.x >> 16);
    av1[2] = bf16_to_f32(ua1.y & 0xFFFFu); av1[3] = bf16_to_f32(ua1.y >> 16);

    // ---- scores = K @ Q^T (swapped): lane q=l15, kv = {4*l4+r, 16+4*l4+r}
    // fragment (row r, d = ds*32+8*l4..+7) at byte sd*1024 + r*32 + 16*(l4&1),
    // sd = 2*ds + (l4>>1)
    f32x4 sc0 = {0.f, 0.f, 0.f, 0.f}, sc1 = {0.f, 0.f, 0.f, 0.f};
#pragma unroll
    for (int ds = 0; ds < 4; ++ds) {
      int boff = (2 * ds + (l4 >> 1)) * 1024 + 16 * (l4 & 1);
      int a0 = boff + l15 * 32;
      int a1 = boff + (16 + l15) * 32;
      bf16x8 kh0 = *(const bf16x8*)((const char*)Khi + a0);
      bf16x8 kl0 = *(const bf16x8*)((const char*)Klo + a0);
      bf16x8 kh1 = *(const bf16x8*)((const char*)Khi + a1);
      bf16x8 kl1 = *(const bf16x8*)((const char*)Klo + a1);
      sc0 = mfma16(kh0, qh[ds], sc0); sc1 = mfma16(kh1, qh[ds], sc1);
      sc0 = mfma16(kh0, ql[ds], sc0); sc1 = mfma16(kh1, ql[ds], sc1);
      sc0 = mfma16(kl0, qh[ds], sc0); sc1 = mfma16(kl1, qh[ds], sc1);
    }

    // ---- adj multiply + online softmax (row q = l15; kv in-lane)
    float p0[4], p1[4];
    float tm = -3.0e38f;
#pragma unroll
    for (int r = 0; r < 4; ++r) {
      p0[r] = sc0[r] * av0[r];
      p1[r] = sc1[r] * av1[r];
      tm = fmaxf(tm, fmaxf(p0[r], p1[r]));
    }
    tm = fmaxf(tm, __shfl_xor(tm, 16));
    tm = fmaxf(tm, __shfl_xor(tm, 32));
    if (__any(tm > m_run + 8.0f)) {             // T13 defer-rescale
      float mn = fmaxf(m_run, tm);
      float scl = __expf(m_run - mn);
      m_run = mn;
      l_run *= scl;
      f32x4 s4;
#pragma unroll
      for (int r = 0; r < 4; ++r) s4[r] = bperm_f(4 * l4 + r, scl);
#pragma unroll
      for (int vf = 0; vf < 8; ++vf)
#pragma unroll
        for (int r = 0; r < 4; ++r) o[vf][r] *= s4[r];
    }
    float ps = 0.f;
#pragma unroll
    for (int r = 0; r < 4; ++r) {
      p0[r] = __expf(p0[r] - m_run); ps += p0[r];
      p1[r] = __expf(p1[r] - m_run); ps += p1[r];
    }
    ps += __shfl_xor(ps, 16);
    ps += __shfl_xor(ps, 32);
    l_run += ps;

    // ---- pack P (trunc-bf16 only; denominator stays exact f32) pi-ordered
    union PU { bf16x8 v; unsigned u[4]; } pah;
#pragma unroll
    for (int i = 0; i < 4; ++i) {
      float fa = (i < 2) ? p0[2 * i] : p1[2 * (i - 2)];
      float fb = (i < 2) ? p0[2 * i + 1] : p1[2 * (i - 2) + 1];
      pah.u[i] = (__float_as_uint(fa) >> 16) |
                 (__float_as_uint(fb) & 0xFFFF0000u);
    }

    // ---- O += P @ V_hi: B-frags via HW transpose read from K_hi (subtiled).
    // per-lane canonical addr: base(vf,h) + lane*8B ->
    //   lane l elem j = K[kv = 16h + 4*l4 + j][d = 16*vf + l15]
    const unsigned short* trb = Khi + lane * 4;
    union VU { bf16x8 v; uint2v u2[2]; } vh[8];
#pragma unroll
    for (int vf = 0; vf < 8; ++vf) {
      vh[vf].u2[0] = tr_read(trb + vf * 512);
      vh[vf].u2[1] = tr_read(trb + vf * 512 + 256);
    }
    asm volatile("s_waitcnt lgkmcnt(0)" ::: "memory");
    __builtin_amdgcn_sched_barrier(0);
#pragma unroll
    for (int vf = 0; vf < 8; ++vf)
      o[vf] = mfma16(pah.v, vh[vf].v, o[vf]);
    // explicit drain of this wave's GLD16s (K[t+1]) + LDS ops before barrier
    asm volatile("s_waitcnt vmcnt(0) lgkmcnt(0)" ::: "memory");
    __syncthreads();   // K[t+1] visible to all; WAR turnover on buf[t&1]
  }

  // ---- epilogue: divide by row sums, stage O in LDS, coalesced f32 writes
  float rinv = 1.0f / l_run;
  f32x4 r4;
#pragma unroll
  for (int r = 0; r < 4; ++r) r4[r] = bperm_f(4 * l4 + r, rinv);
  float* wbase = (float*)SM + w * 2048;         // [16][128] f32 per wave
#pragma unroll
  for (int vf = 0; vf < 8; ++vf)
#pragma unroll
    for (int r = 0; r < 4; ++r)
      wbase[(4 * l4 + r) * 128 + vf * 16 + l15] = o[vf][r] * r4[r];
  __syncthreads();
#pragma unroll
  for (int p = 0; p < 4; ++p) {
    int row = p * 4 + l4;
    f32x4 v0 = *(const f32x4*)(wbase + row * 128 + l15 * 8);
    f32x4 v1 = *(const f32x4*)(wbase + row * 128 + l15 * 8 + 4);
    size_t mg = (size_t)bb * 512 + q0 + w * 16 + row;
    float* op = out + mg * 512 + hd * 128 + l15 * 8;
    *(f32x4*)op = v0;
    *(f32x4*)(op + 4) = v1;
  }
}

// ---------------------------------------------------------------------------
// Kernel 6: LayerNorm (over C=512) + exact-erf GELU, in place on d_out.
// ---------------------------------------------------------------------------
__global__ __launch_bounds__(256) void ln_gelu_kernel(
    float* __restrict__ io, const float* __restrict__ gamma,
    const float* __restrict__ beta) {
  int w = threadIdx.x >> 6, lane = threadIdx.x & 63;
  size_t row = (size_t)blockIdx.x * 4 + w;
  float* p = io + row * 512;
  f32x4 x0 = *(const f32x4*)(p + lane * 8);
  f32x4 x1 = *(const f32x4*)(p + lane * 8 + 4);
  float s = x0[0] + x0[1] + x0[2] + x0[3] + x1[0] + x1[1] + x1[2] + x1[3];
#pragma unroll
  for (int off = 32; off >= 1; off >>= 1) s += __shfl_xor(s, off);
  float mu = s * (1.0f / 512.0f);
  float vs = 0.f;
#pragma unroll
  for (int e = 0; e < 4; ++e) {
    float d0 = x0[e] - mu; vs += d0 * d0;
    float d1 = x1[e] - mu; vs += d1 * d1;
  }
#pragma unroll
  for (int off = 32; off >= 1; off >>= 1) vs += __shfl_xor(vs, off);
  float rs = rsqrtf(vs * (1.0f / 512.0f) + 1e-5f);
  f32x4 g0 = *(const f32x4*)(gamma + lane * 8);
  f32x4 g1 = *(const f32x4*)(gamma + lane * 8 + 4);
  f32x4 b0 = *(const f32x4*)(beta + lane * 8);
  f32x4 b1 = *(const f32x4*)(beta + lane * 8 + 4);
  f32x4 y0, y1;
#pragma unroll
  for (int e = 0; e < 4; ++e) {
    float y = (x0[e] - mu) * rs * g0[e] + b0[e];
    y0[e] = 0.5f * y * (1.0f + erff(y * 0.70710678118654752f));
    float z = (x1[e] - mu) * rs * g1[e] + b1[e];
    y1[e] = 0.5f * z * (1.0f + erff(z * 0.70710678118654752f));
  }
  *(f32x4*)(p + lane * 8) = y0;
  *(f32x4*)(p + lane * 8 + 4) = y1;
}

// ---------------------------------------------------------------------------
// Host launcher.  Inputs: [0]=t [1]=h [2]=W [3]=b [4]=adj [5]=gamma [6]=beta
// Workspace (~129 MB):
//   h_hi   = ws + 0          (16.7M u16)  -- dead after proj; reused for adj_bf
//   h_lo   = ws + 16777216
//   hp_hi  = ws + 33554432
//   hp_lo  = ws + 50331648
//   Wt_hi  = ws + 67108864   (262144 u16)
//   Wt_lo  = ws + 67371008
//   adj_bf = ws + 0          (262144 u16, written after proj_gemm)
// ---------------------------------------------------------------------------
extern "C" void kernel_launch(void* const* d_in, const int* in_sizes, int n_in,
                              void* d_out, int out_size, void* d_ws, size_t ws_size,
                              hipStream_t stream) {
  const float* h     = (const float*)d_in[1];
  const float* W     = (const float*)d_in[2];
  const float* bias  = (const float*)d_in[3];
  const float* adj   = (const float*)d_in[4];
  const float* gamma = (const float*)d_in[5];
  const float* beta  = (const float*)d_in[6];
  float* out = (float*)d_out;

  unsigned short* ws = (unsigned short*)d_ws;
  unsigned short* h_hi   = ws;
  unsigned short* h_lo   = ws + 16777216;
  unsigned short* hp_hi  = ws + 33554432;
  unsigned short* hp_lo  = ws + 50331648;
  unsigned short* Wt_hi  = ws + 67108864;
  unsigned short* Wt_lo  = ws + 67371008;
  unsigned short* adj_bf = ws;                  // reuse dead h_hi region

  cast_split_h<<<8192, 256, 0, stream>>>(h, h_hi, h_lo);
  cast_split_Wt<<<1024, 256, 0, stream>>>(W, Wt_hi, Wt_lo);
  proj_gemm<<<1024, 256, 0, stream>>>(h_hi, h_lo, Wt_hi, Wt_lo, bias, hp_hi, hp_lo);
  cast_adj<<<128, 256, 0, stream>>>(adj, adj_bf);   // after proj (h_hi dead)
  attn_kernel<<<2048, 256, 0, stream>>>(hp_hi, hp_lo, adj_bf, out);
  ln_gelu_kernel<<<8192, 256, 0, stream>>>(out, gamma, beta);
}